// Round 9
// baseline (1905.803 us; speedup 1.0000x reference)
//
#include <hip/hip_runtime.h>
#include <hip/hip_bf16.h>
#include <math.h>

#define B_ 16
#define S_ 256
#define T_ 800
#define V_ 256
#define D_ 512
#define M_ 80
#define H_ 1024
#define NH_ 4
#define HD_ 128
#define EH_ 256

using bf16x8 = __attribute__((ext_vector_type(8))) short;
using f32x4  = __attribute__((ext_vector_type(4))) float;
typedef _Float16 half8 __attribute__((ext_vector_type(8)));

__device__ __forceinline__ float sigf(float x) { return 1.f / (1.f + __expf(-x)); }
__device__ __forceinline__ float tanhfast(float x) {
    float e = __expf(2.f * x);
    return 1.f - 2.f / (e + 1.f);
}

__device__ __forceinline__ unsigned short f2bf(float f) {
    unsigned int u = __float_as_uint(f);
    unsigned int r = (u + 0x7FFFu + ((u >> 16) & 1u)) >> 16;
    return (unsigned short)r;
}
__device__ __forceinline__ float bf2f(unsigned short u) {
    return __uint_as_float(((unsigned int)u) << 16);
}
__device__ __forceinline__ unsigned short h2u(_Float16 x) {
    union { _Float16 f; unsigned short u; } c; c.f = x; return c.u;
}

// LDS-only barrier (no vmcnt drain); sched_barrier fences motion (rule #18).
#define LDS_BAR() do {                                        \
    asm volatile("s_waitcnt lgkmcnt(0)" ::: "memory");        \
    __builtin_amdgcn_s_barrier();                             \
    __builtin_amdgcn_sched_barrier(0);                        \
} while (0)

__device__ __forceinline__ void gl_lds16(const unsigned short* g, unsigned short* l) {
    __builtin_amdgcn_global_load_lds((const __attribute__((address_space(1))) void*)g,
                                     (__attribute__((address_space(3))) void*)l, 16, 0, 0);
}

// ---------------- MFMA bf16 GEMM: C = A(M,K) @ B(N,K)^T --------------------
// epi: 0 fp32(+bias), 1 conv BN+ReLU fp32, 2 bf16(+bias), 3 v^T bf16, 4 fp32 col<80
__global__ __launch_bounds__(256) void gemm_mfma(
    const unsigned short* __restrict__ A, const unsigned short* __restrict__ Bw,
    void* __restrict__ Cv, const float* __restrict__ bias,
    int M, int N, int K, int ldc, int epi,
    const float* __restrict__ cb, const float* __restrict__ gam,
    const float* __restrict__ bet, const float* __restrict__ mu,
    const float* __restrict__ va)
{
    __shared__ unsigned short As[4096];
    __shared__ unsigned short Bs[4096];
    const int tid = threadIdx.x, w = tid >> 6, lane = tid & 63;
    const int bm = blockIdx.y * 128, bn = blockIdx.x * 128;
    const int wr = w >> 1, wc = w & 1;

    f32x4 acc[4][4];
#pragma unroll
    for (int m = 0; m < 4; ++m)
#pragma unroll
        for (int n = 0; n < 4; ++n) acc[m][n] = (f32x4){0.f, 0.f, 0.f, 0.f};

    const int r0 = w * 16 + (lane >> 2);
    const int k8 = (lane & 3) * 8;
    const unsigned short* Ag = A + (size_t)(bm + r0) * K + k8;
    const unsigned short* Bg = Bw + (size_t)(bn + r0) * K + k8;
    unsigned short* Al = As + w * 512;
    unsigned short* Bl = Bs + w * 512;

    for (int k0 = 0; k0 < K; k0 += 32) {
        __syncthreads();
        gl_lds16(Ag + k0, Al);
        gl_lds16(Ag + (size_t)64 * K + k0, Al + 2048);
        gl_lds16(Bg + k0, Bl);
        gl_lds16(Bg + (size_t)64 * K + k0, Bl + 2048);
        __syncthreads();
        bf16x8 a[4], b[4];
#pragma unroll
        for (int m = 0; m < 4; ++m)
            a[m] = *(const bf16x8*)(As + (wr * 64 + m * 16 + (lane & 15)) * 32 + (lane >> 4) * 8);
#pragma unroll
        for (int n = 0; n < 4; ++n)
            b[n] = *(const bf16x8*)(Bs + (wc * 64 + n * 16 + (lane & 15)) * 32 + (lane >> 4) * 8);
#pragma unroll
        for (int m = 0; m < 4; ++m)
#pragma unroll
            for (int n = 0; n < 4; ++n)
                acc[m][n] = __builtin_amdgcn_mfma_f32_16x16x32_bf16(a[m], b[n], acc[m][n], 0, 0, 0);
    }

    const int cr = (lane >> 4) * 4, ccol = lane & 15;
#pragma unroll
    for (int m = 0; m < 4; ++m)
#pragma unroll
        for (int n = 0; n < 4; ++n) {
            const int col = bn + wc * 64 + n * 16 + ccol;
            const float bv = (bias && !(epi == 4 && col >= 80)) ? bias[col] : 0.f;
#pragma unroll
            for (int j = 0; j < 4; ++j) {
                const int row = bm + wr * 64 + m * 16 + cr + j;
                float v = acc[m][n][j] + bv;
                if (epi == 1) {
                    float x = v + cb[col];
                    v = fmaxf(0.f, gam[col] * (x - mu[col]) * rsqrtf(va[col] + 1e-5f) + bet[col]);
                }
                if (epi == 2) {
                    ((unsigned short*)Cv)[(size_t)row * ldc + col] = f2bf(v);
                } else if (epi == 3) {
                    const int bb2 = row >> 8, ss = row & 255, hh = col >> 7, dd = col & 127;
                    ((unsigned short*)Cv)[((size_t)(bb2 * 4 + hh) * 128 + dd) * 256 + ss] = f2bf(v);
                } else if (epi == 4) {
                    if (col < 80) ((float*)Cv)[(size_t)row * ldc + col] = v;
                } else {
                    ((float*)Cv)[(size_t)row * ldc + col] = v;
                }
            }
        }
}

// ---------------- attention QK^T ------------------------------------------
__global__ __launch_bounds__(256) void attn_qk(
    const unsigned short* __restrict__ q, const unsigned short* __restrict__ k,
    float* __restrict__ scores)
{
    __shared__ unsigned short As[4096];
    __shared__ unsigned short Bs[4096];
    const int tid = threadIdx.x, w = tid >> 6, lane = tid & 63;
    const int bm = blockIdx.y * 128, bn = blockIdx.x * 128;
    const int z = blockIdx.z, b = z >> 2, h = z & 3;
    const int wr = w >> 1, wc = w & 1;

    const unsigned short* A  = q + ((size_t)b * T_) * 512 + h * 128;
    const unsigned short* Bw = k + ((size_t)b * S_) * 512 + h * 128;

    f32x4 acc[4][4];
#pragma unroll
    for (int m = 0; m < 4; ++m)
#pragma unroll
        for (int n = 0; n < 4; ++n) acc[m][n] = (f32x4){0.f, 0.f, 0.f, 0.f};

    const int r0 = w * 16 + (lane >> 2);
    const int k8 = (lane & 3) * 8;
    const unsigned short* Ag = A + (size_t)(bm + r0) * 512 + k8;
    const unsigned short* Bg = Bw + (size_t)(bn + r0) * 512 + k8;
    unsigned short* Al = As + w * 512;
    unsigned short* Bl = Bs + w * 512;

    for (int k0 = 0; k0 < 128; k0 += 32) {
        __syncthreads();
        gl_lds16(Ag + k0, Al);
        gl_lds16(Ag + (size_t)64 * 512 + k0, Al + 2048);
        gl_lds16(Bg + k0, Bl);
        gl_lds16(Bg + (size_t)64 * 512 + k0, Bl + 2048);
        __syncthreads();
        bf16x8 a[4], bfr[4];
#pragma unroll
        for (int m = 0; m < 4; ++m)
            a[m] = *(const bf16x8*)(As + (wr * 64 + m * 16 + (lane & 15)) * 32 + (lane >> 4) * 8);
#pragma unroll
        for (int n = 0; n < 4; ++n)
            bfr[n] = *(const bf16x8*)(Bs + (wc * 64 + n * 16 + (lane & 15)) * 32 + (lane >> 4) * 8);
#pragma unroll
        for (int m = 0; m < 4; ++m)
#pragma unroll
            for (int n = 0; n < 4; ++n)
                acc[m][n] = __builtin_amdgcn_mfma_f32_16x16x32_bf16(a[m], bfr[n], acc[m][n], 0, 0, 0);
    }

    const int cr = (lane >> 4) * 4, ccol = lane & 15;
#pragma unroll
    for (int m = 0; m < 4; ++m)
#pragma unroll
        for (int n = 0; n < 4; ++n) {
            const int col = bn + wc * 64 + n * 16 + ccol;
#pragma unroll
            for (int j = 0; j < 4; ++j) {
                const int row = bm + wr * 64 + m * 16 + cr + j;
                if (row < T_)
                    scores[((size_t)z * T_ + row) * 256 + col] = acc[m][n][j] * 0.08838834764831843f;
            }
        }
}

// ---------------- softmax over s (wave per row) ----------------------------
__global__ __launch_bounds__(256) void attn_sm(
    const float* __restrict__ scores, unsigned short* __restrict__ probs)
{
    const int row = blockIdx.x * 4 + (threadIdx.x >> 6);
    const int lane = threadIdx.x & 63;
    const float4 v = *(const float4*)(scores + (size_t)row * 256 + lane * 4);
    float m = fmaxf(fmaxf(v.x, v.y), fmaxf(v.z, v.w));
    for (int off = 32; off; off >>= 1) m = fmaxf(m, __shfl_xor(m, off));
    float ex = __expf(v.x - m), ey = __expf(v.y - m), ez = __expf(v.z - m), ew = __expf(v.w - m);
    float sum = ex + ey + ez + ew;
    for (int off = 32; off; off >>= 1) sum += __shfl_xor(sum, off);
    const float inv = 1.f / sum;
    ushort4 o;
    o.x = f2bf(ex * inv); o.y = f2bf(ey * inv); o.z = f2bf(ez * inv); o.w = f2bf(ew * inv);
    *(ushort4*)(probs + (size_t)row * 256 + lane * 4) = o;
}

// ---------------- attention PV --------------------------------------------
__global__ __launch_bounds__(256) void attn_pv(
    const unsigned short* __restrict__ probs, const unsigned short* __restrict__ vT,
    unsigned short* __restrict__ ctx)
{
    __shared__ unsigned short As[4096];
    __shared__ unsigned short Bs[4096];
    const int tid = threadIdx.x, w = tid >> 6, lane = tid & 63;
    const int bm = blockIdx.y * 128;
    const int z = blockIdx.z, b = z >> 2, h = z & 3;
    const int wr = w >> 1, wc = w & 1;

    const unsigned short* A  = probs + (size_t)z * T_ * 256;
    const unsigned short* Bw = vT + (size_t)z * 128 * 256;

    f32x4 acc[4][4];
#pragma unroll
    for (int m = 0; m < 4; ++m)
#pragma unroll
        for (int n = 0; n < 4; ++n) acc[m][n] = (f32x4){0.f, 0.f, 0.f, 0.f};

    const int r0 = w * 16 + (lane >> 2);
    const int k8 = (lane & 3) * 8;
    const unsigned short* Ag = A + (size_t)(bm + r0) * 256 + k8;
    const unsigned short* Bg = Bw + (size_t)r0 * 256 + k8;
    unsigned short* Al = As + w * 512;
    unsigned short* Bl = Bs + w * 512;

    for (int k0 = 0; k0 < 256; k0 += 32) {
        __syncthreads();
        gl_lds16(Ag + k0, Al);
        gl_lds16(Ag + (size_t)64 * 256 + k0, Al + 2048);
        gl_lds16(Bg + k0, Bl);
        gl_lds16(Bg + (size_t)64 * 256 + k0, Bl + 2048);
        __syncthreads();
        bf16x8 a[4], bfr[4];
#pragma unroll
        for (int m = 0; m < 4; ++m)
            a[m] = *(const bf16x8*)(As + (wr * 64 + m * 16 + (lane & 15)) * 32 + (lane >> 4) * 8);
#pragma unroll
        for (int n = 0; n < 4; ++n)
            bfr[n] = *(const bf16x8*)(Bs + (wc * 64 + n * 16 + (lane & 15)) * 32 + (lane >> 4) * 8);
#pragma unroll
        for (int m = 0; m < 4; ++m)
#pragma unroll
            for (int n = 0; n < 4; ++n)
                acc[m][n] = __builtin_amdgcn_mfma_f32_16x16x32_bf16(a[m], bfr[n], acc[m][n], 0, 0, 0);
    }

    const int cr = (lane >> 4) * 4, ccol = lane & 15;
#pragma unroll
    for (int m = 0; m < 4; ++m)
#pragma unroll
        for (int n = 0; n < 4; ++n) {
            const int col = wc * 64 + n * 16 + ccol;
#pragma unroll
            for (int j = 0; j < 4; ++j) {
                const int row = bm + wr * 64 + m * 16 + cr + j;
                if (row < T_)
                    ctx[((size_t)b * T_ + row) * 512 + h * 128 + col] = f2bf(acc[m][n][j]);
            }
        }
}

// ---------------- elementwise / conversion kernels -------------------------
__global__ void embed_k(const int* __restrict__ txt, const float* __restrict__ emb,
                        float* __restrict__ xs)
{
    int idx = blockIdx.x * 256 + threadIdx.x;
    if (idx >= B_ * S_ * D_) return;
    int bs = idx >> 9, dd = idx & 511;
    xs[idx] = emb[(size_t)txt[bs] * D_ + dd];
}

__global__ void im2col_bf(const float* __restrict__ in, unsigned short* __restrict__ out)
{
    int idx = blockIdx.x * 256 + threadIdx.x;
    if (idx >= B_ * S_ * 2560) return;
    int r = idx / 2560, cc = idx % 2560;
    int din = cc / 5, kk = cc % 5;
    int b = r >> 8, s = r & 255;
    int sp = s + kk - 2;
    float v = (sp >= 0 && sp < S_) ? in[((size_t)b * S_ + sp) * D_ + din] : 0.f;
    out[idx] = f2bf(v);
}

__global__ void transp_bf(const float* __restrict__ in, unsigned short* __restrict__ out)
{
    int idx = blockIdx.x * 256 + threadIdx.x;
    if (idx >= B_ * S_ * D_) return;
    int d = idx & 511;
    int sb = idx >> 9;
    int s = sb >> 4, b = sb & 15;
    out[idx] = f2bf(in[((size_t)b * S_ + s) * D_ + d]);
}

// hist (f16, [dir][b][s][256]) -> enc (bf16, [b][s][512])
__global__ void hist2enc(const _Float16* __restrict__ hist, unsigned short* __restrict__ enc)
{
    int idx = blockIdx.x * 256 + threadIdx.x;
    if (idx >= B_ * S_ * D_) return;
    int d = idx & 511;
    int bs = idx >> 9;
    int b = bs >> 8, s = bs & 255;
    int dir = d >> 8, hid = d & 255;
    enc[idx] = f2bf((float)hist[(((size_t)(dir * 16 + b) * 256 + s) * 256) + hid]);
}

// ---- single fused weight-conversion kernel (10 launches -> 1) ----
__global__ void cvt_all(
    const float* __restrict__ conv_w, const float* __restrict__ Wih_f,
    const float* __restrict__ Wih_b, const float* __restrict__ Wk,
    const float* __restrict__ Wv, const float* __restrict__ Wq,
    const float* __restrict__ Wo, const float* __restrict__ Wih1,
    const float* __restrict__ Wih2, const float* __restrict__ melW,
    unsigned short* __restrict__ cWc, unsigned short* __restrict__ cWif,
    unsigned short* __restrict__ cWib, unsigned short* __restrict__ cWk,
    unsigned short* __restrict__ cWv, unsigned short* __restrict__ cWq,
    unsigned short* __restrict__ cWo, unsigned short* __restrict__ cW1,
    unsigned short* __restrict__ cW2, unsigned short* __restrict__ cWm)
{
    int idx = blockIdx.x * 256 + threadIdx.x;
    if (idx < 3932160) { cWc[idx] = f2bf(conv_w[idx]); return; }
    idx -= 3932160;
    if (idx < 524288) { cWif[idx] = f2bf(Wih_f[idx]); return; }
    idx -= 524288;
    if (idx < 524288) { cWib[idx] = f2bf(Wih_b[idx]); return; }
    idx -= 524288;
    if (idx < 262144) { cWk[idx] = f2bf(Wk[idx]); return; }
    idx -= 262144;
    if (idx < 262144) { cWv[idx] = f2bf(Wv[idx]); return; }
    idx -= 262144;
    if (idx < 49152) {
        int r = idx / 96, k = idx - r * 96;
        cWq[idx] = (k < 80) ? f2bf(Wq[(size_t)r * 80 + k]) : 0;
        return;
    }
    idx -= 49152;
    if (idx < 262144) { cWo[idx] = f2bf(Wo[idx]); return; }
    idx -= 262144;
    if (idx < 1867776) {
        int n = idx / 608, k = idx - n * 608;
        int orig = (n < 1024) ? n : n + 1024;
        cW1[idx] = (k < 592) ? f2bf(Wih1[(size_t)orig * 592 + k]) : 0;
        return;
    }
    idx -= 1867776;
    if (idx < 3145728) {
        int n = idx >> 10, k = idx & 1023;
        int orig = (n < 1024) ? n : n + 1024;
        cW2[idx] = f2bf(Wih2[(size_t)orig * 1024 + k]);
        return;
    }
    idx -= 3145728;
    if (idx < 131072) {
        int r = idx >> 10, k = idx & 1023;
        cWm[idx] = (r < 80) ? f2bf(melW[(size_t)r * 1024 + k]) : 0;
        return;
    }
}

__global__ void decin_k2(const float* __restrict__ mel, unsigned short* __restrict__ din,
                         unsigned short* __restrict__ xcat)
{
    int idx = blockIdx.x * 256 + threadIdx.x;
    if (idx >= B_ * T_ * 96) return;
    int r = idx / 96, j = idx - r * 96;
    int b = r / T_, t = r - b * T_;
    float v = (j < M_ && t > 0) ? mel[((size_t)b * T_ + t - 1) * M_ + j] : 0.f;
    unsigned short bv = f2bf(v);
    din[(size_t)r * 96 + j] = bv;
    xcat[(size_t)r * 608 + 512 + j] = bv;
}

// decoder cell: gates bf16 [rows][3072] = [i;g;o], out bf16; 2 cols/thread
__global__ void dec_cellb2(const unsigned short* __restrict__ g, const float* __restrict__ b,
                           unsigned short* __restrict__ h, int rows)
{
    int idx = blockIdx.x * 256 + threadIdx.x;
    if (idx >= rows * 512) return;
    int r = idx >> 9, j2 = (idx & 511) * 2;
    const unsigned short* gr = g + (size_t)r * 3072;
    ushort2 vi = *(const ushort2*)(gr + j2);
    ushort2 vg = *(const ushort2*)(gr + 1024 + j2);
    ushort2 vo = *(const ushort2*)(gr + 2048 + j2);
    float i0 = sigf(bf2f(vi.x) + b[j2]),          i1 = sigf(bf2f(vi.y) + b[j2 + 1]);
    float g0 = tanhfast(bf2f(vg.x) + b[2048 + j2]), g1 = tanhfast(bf2f(vg.y) + b[2048 + j2 + 1]);
    float o0 = sigf(bf2f(vo.x) + b[3072 + j2]),   o1 = sigf(bf2f(vo.y) + b[3072 + j2 + 1]);
    ushort2 o;
    o.x = f2bf(o0 * tanhfast(i0 * g0));
    o.y = f2bf(o1 * tanhfast(i1 * g1));
    *(ushort2*)(h + (size_t)r * 1024 + j2) = o;
}

__global__ __launch_bounds__(256) void stop_head(
    const unsigned short* __restrict__ h2, const float* __restrict__ sw,
    const float* __restrict__ sb, float* __restrict__ out)
{
    int row = blockIdx.x * 4 + (threadIdx.x >> 6);
    int lane = threadIdx.x & 63;
    const unsigned short* hr = h2 + (size_t)row * H_;
    float acc = 0.f;
#pragma unroll
    for (int i = 0; i < H_; i += 64) acc += bf2f(hr[i + lane]) * sw[i + lane];
    for (int off = 32; off; off >>= 1) acc += __shfl_xor(acc, off);
    if (lane == 0) out[row] = acc + sb[0];
}

// ---------------- persistent LSTM: A/B chain software pipeline -------------
// 4 blocks (dir x half). Batches split into chains A(0-7)/B(8-15) -- fully
// independent recurrences. Per iter:
//   A.update(s); A.publish | B.spin(s-1); B.MFMA(s-1) | B.update(s);
//   B.publish | A.spin(s); A.MFMA(s)
// Each chain's LLC publish->spin RT is covered by the OTHER chain's compute.
// Publish = one u32 {tag16,h16} relaxed sc1 atomic (tag+data same word ->
// no ordering needed). Parity slots; skew<=1 by dependence chain.
__global__ __launch_bounds__(1024, 4) void lstm_persist7(
    const float* __restrict__ gi_f, const float* __restrict__ gi_b,
    const float* __restrict__ Wf, const float* __restrict__ Wb,
    _Float16* __restrict__ hist,          // [2][16][256][256] f16
    unsigned int* __restrict__ hstage)    // [2 slot][2 chain][2 dir][2 half][1024]
{
    const int blk = blockIdx.x;
    const int dir = blk >> 1, half = blk & 1;
    const float* gi = dir ? gi_b : gi_f;
    const float* W  = dir ? Wb : Wf;
    const int tid = threadIdx.x, wid = tid >> 6, lane = tid & 63;
    const int l15 = lane & 15, q = lane >> 4;

    __shared__ _Float16 h_lds[16][264];
    __shared__ float exch[512][17];

    // full-K weight fragments: w0 = gate tile wid, w1 = tile wid+16
    half8 w0[8], w1[8];
    {
        const int gt0 = wid >> 3, hb0 = wid & 7;
        const int gt1 = (wid + 16) >> 3;
        const float* wr0 = W + (size_t)(gt0 * 256 + half * 128 + hb0 * 16 + l15) * 256;
        const float* wr1 = W + (size_t)(gt1 * 256 + half * 128 + hb0 * 16 + l15) * 256;
#pragma unroll
        for (int ks = 0; ks < 8; ++ks) {
            half8 a, b;
#pragma unroll
            for (int j = 0; j < 8; ++j) {
                a[j] = (_Float16)wr0[ks * 32 + q * 8 + j];
                b[j] = (_Float16)wr1[ks * 32 + q * 8 + j];
            }
            w0[ks] = a; w1[ks] = b;
        }
    }
    for (int i = tid; i < 16 * 264; i += 1024) ((_Float16*)h_lds)[i] = (_Float16)0.f;
    for (int i = tid; i < 512 * 17; i += 1024) ((float*)exch)[i] = 0.f;

    const int hid = tid & 127;
    const int ba  = tid >> 7;       // chain A batch 0..7
    const int bb  = ba + 8;         // chain B batch
    const int gh  = half * 128 + hid;
    const int pc  = (half ^ 1) * 128 + hid;
    float cA = 0.f, cB = 0.f;

    const int exr0 = (wid >> 3) * 128 + (wid & 7) * 16 + l15;
    const int exr1 = ((wid + 16) >> 3) * 128 + (wid & 7) * 16 + l15;

    // hstage layout: ((slot*2 + chain)*2 + dir)*2 + half, then [ba*128+hid]
    const int ownA = ((dir) * 2 + half) * 1024 + (ba << 7) + hid;             // chain 0
    const int parA = ((dir) * 2 + (half ^ 1)) * 1024 + (ba << 7) + hid;
    const int ownB = 4096 + ownA;                                             // chain 1
    const int parB = 4096 + parA;

    // gi prefetch for step 0
    float gpA[4], gpB[4];
    {
        const int s0 = dir ? 255 : 0;
        const float* g0 = gi + ((size_t)s0 * 16 + ba) * 1024 + gh;
        const float* g1 = gi + ((size_t)s0 * 16 + bb) * 1024 + gh;
#pragma unroll
        for (int g2 = 0; g2 < 4; ++g2) { gpA[g2] = g0[g2 * 256]; gpB[g2] = g1[g2 * 256]; }
    }
    __syncthreads();

    for (int step = 0; step < 256; ++step) {
        const int s = dir ? (255 - step) : step;
        const unsigned int tag = (unsigned int)(step + 1);
        const int slot = (step & 1) * 8192;

        // ---- phase 1: A.update(step) (exch cols 0-7 = Whh@h_A(step-1)) ----
        float hA;
        {
            float xi = exch[hid][ba] + gpA[0];
            float xf = exch[128 + hid][ba] + gpA[1];
            float xg = exch[256 + hid][ba] + gpA[2];
            float xo = exch[384 + hid][ba] + gpA[3];
            float ig = sigf(xi), fg = sigf(xf), gg = tanhfast(xg), og = sigf(xo);
            cA = fg * cA + ig * gg; hA = og * tanhfast(cA);
        }
        h_lds[ba][gh] = (_Float16)hA;
        __hip_atomic_store(&hstage[slot + ownA], (tag << 16) | (unsigned int)h2u((_Float16)hA),
                           __ATOMIC_RELAXED, __HIP_MEMORY_SCOPE_AGENT);
        hist[(((size_t)(dir * 16 + ba) * 256 + s) * 256) + gh] = (_Float16)hA;
        if (step < 255) {
            const int s2 = dir ? (254 - step) : (step + 1);
            const float* g0 = gi + ((size_t)s2 * 16 + ba) * 1024 + gh;
#pragma unroll
            for (int g2 = 0; g2 < 4; ++g2) gpA[g2] = g0[g2 * 256];
        }

        // ---- phase 2: B.spin(step-1): fill h_lds[bb][pc] ----
        if (step > 0) {
            const unsigned int wantp = (unsigned int)step;
            const int pslot = ((step - 1) & 1) * 8192;
            unsigned int pv;
            do {
                pv = __hip_atomic_load(&hstage[pslot + parB],
                                       __ATOMIC_RELAXED, __HIP_MEMORY_SCOPE_AGENT);
            } while ((pv >> 16) != wantp);
            *(unsigned short*)&h_lds[bb][pc] = (unsigned short)(pv & 0xFFFF);
        }
        LDS_BAR();

        // ---- phase 3: B.MFMA(step-1) -> exch cols 8-15 ----
        {
            f32x4 a0 = (f32x4){0.f, 0.f, 0.f, 0.f};
            f32x4 a1 = (f32x4){0.f, 0.f, 0.f, 0.f};
            const _Float16* hrow = &h_lds[l15][0];
#pragma unroll
            for (int ks = 0; ks < 8; ++ks) {
                half8 a = *(const half8*)(hrow + ks * 32 + q * 8);
                a0 = __builtin_amdgcn_mfma_f32_16x16x32_f16(a, w0[ks], a0, 0, 0, 0);
                a1 = __builtin_amdgcn_mfma_f32_16x16x32_f16(a, w1[ks], a1, 0, 0, 0);
            }
            if (q >= 2) {
                *(f32x4*)&exch[exr0][q * 4] = a0;
                *(f32x4*)&exch[exr1][q * 4] = a1;
            }
        }
        LDS_BAR();

        // ---- phase 4: B.update(step) ----
        float hB;
        {
            float xi = exch[hid][bb] + gpB[0];
            float xf = exch[128 + hid][bb] + gpB[1];
            float xg = exch[256 + hid][bb] + gpB[2];
            float xo = exch[384 + hid][bb] + gpB[3];
            float ig = sigf(xi), fg = sigf(xf), gg = tanhfast(xg), og = sigf(xo);
            cB = fg * cB + ig * gg; hB = og * tanhfast(cB);
        }
        h_lds[bb][gh] = (_Float16)hB;
        __hip_atomic_store(&hstage[slot + ownB], (tag << 16) | (unsigned int)h2u((_Float16)hB),
                           __ATOMIC_RELAXED, __HIP_MEMORY_SCOPE_AGENT);
        hist[(((size_t)(dir * 16 + bb) * 256 + s) * 256) + gh] = (_Float16)hB;
        if (step < 255) {
            const int s2 = dir ? (254 - step) : (step + 1);
            const float* g1 = gi + ((size_t)s2 * 16 + bb) * 1024 + gh;
#pragma unroll
            for (int g2 = 0; g2 < 4; ++g2) gpB[g2] = g1[g2 * 256];
        }

        // ---- phase 5: A.spin(step): fill h_lds[ba][pc] ----
        {
            unsigned int pv;
            do {
                pv = __hip_atomic_load(&hstage[slot + parA],
                                       __ATOMIC_RELAXED, __HIP_MEMORY_SCOPE_AGENT);
            } while ((pv >> 16) != tag);
            *(unsigned short*)&h_lds[ba][pc] = (unsigned short)(pv & 0xFFFF);
        }
        LDS_BAR();

        // ---- phase 6: A.MFMA(step) -> exch cols 0-7 ----
        {
            f32x4 a0 = (f32x4){0.f, 0.f, 0.f, 0.f};
            f32x4 a1 = (f32x4){0.f, 0.f, 0.f, 0.f};
            const _Float16* hrow = &h_lds[l15][0];
#pragma unroll
            for (int ks = 0; ks < 8; ++ks) {
                half8 a = *(const half8*)(hrow + ks * 32 + q * 8);
                a0 = __builtin_amdgcn_mfma_f32_16x16x32_f16(a, w0[ks], a0, 0, 0, 0);
                a1 = __builtin_amdgcn_mfma_f32_16x16x32_f16(a, w1[ks], a1, 0, 0, 0);
            }
            if (q < 2) {
                *(f32x4*)&exch[exr0][q * 4] = a0;
                *(f32x4*)&exch[exr1][q * 4] = a1;
            }
        }
        LDS_BAR();
    }
}

// ---------------- host orchestration --------------------------------------
static inline void launch_mfma(hipStream_t st, const unsigned short* A, const unsigned short* B,
                               void* C, const float* bias, int M, int N, int K, int ldc, int epi = 0,
                               const float* cb = nullptr, const float* gam = nullptr,
                               const float* bet = nullptr, const float* mu = nullptr,
                               const float* va = nullptr)
{
    dim3 grid(N / 128, M / 128);
    gemm_mfma<<<grid, 256, 0, st>>>(A, B, C, bias, M, N, K, ldc, epi, cb, gam, bet, mu, va);
}

extern "C" void kernel_launch(void* const* d_in, const int* in_sizes, int n_in,
                              void* d_out, int out_size, void* d_ws, size_t ws_size,
                              hipStream_t stream)
{
    const int*   text   = (const int*)d_in[0];
    const float* mel_t  = (const float*)d_in[1];
    const float* emb    = (const float*)d_in[2];
    const float* conv_w = (const float*)d_in[3];
    const float* conv_b = (const float*)d_in[4];
    const float* bn_g   = (const float*)d_in[5];
    const float* bn_b   = (const float*)d_in[6];
    const float* bn_m   = (const float*)d_in[7];
    const float* bn_v   = (const float*)d_in[8];
    const float* Wih_f  = (const float*)d_in[9];
    const float* Whh_f  = (const float*)d_in[10];
    const float* b_f    = (const float*)d_in[11];
    const float* Wih_b  = (const float*)d_in[12];
    const float* Whh_b  = (const float*)d_in[13];
    const float* b_b    = (const float*)d_in[14];
    const float* Wq     = (const float*)d_in[15];
    const float* bq     = (const float*)d_in[16];
    const float* Wk     = (const float*)d_in[17];
    const float* bk     = (const float*)d_in[18];
    const float* Wv     = (const float*)d_in[19];
    const float* bv     = (const float*)d_in[20];
    const float* Wo     = (const float*)d_in[21];
    const float* bo     = (const float*)d_in[22];
    const float* Wih1   = (const float*)d_in[23];
    const float* b1     = (const float*)d_in[24];
    const float* Wih2   = (const float*)d_in[25];
    const float* b2     = (const float*)d_in[26];
    const float* melW   = (const float*)d_in[27];
    const float* melb   = (const float*)d_in[28];
    const float* stopW  = (const float*)d_in[29];
    const float* stopb  = (const float*)d_in[30];
    float* out = (float*)d_out;
    (void)in_sizes; (void)n_in; (void)out_size; (void)ws_size;

    float* ws = (float*)d_ws;
    float* big  = ws;                       // 13107200 f: im2col | scores | h2b/h1b
    float* pool = ws + 13107200;

    unsigned int* hstage = (unsigned int*)(ws + 6000000);   // 16384 u32, 64KB

    // phase A/B (encoder)
    float*          gi_f   = pool + 0;
    float*          gi_b   = pool + 4194304;
    unsigned short* enc_bf = (unsigned short*)(pool + 8388608);
    float*          P0     = pool + 9437184;
    float*          P1     = pool + 11534336;
    unsigned short* xsT    = (unsigned short*)(pool + 13631488);
    _Float16*       hist   = (_Float16*)(pool + 14155776);     // 4MB f16
    // phase C (attention)
    unsigned short* kbf    = (unsigned short*)(pool + 0);
    unsigned short* vT     = (unsigned short*)(pool + 1048576);
    unsigned short* qbf    = (unsigned short*)(pool + 2097152);
    unsigned short* probs  = (unsigned short*)(pool + 9437184);
    unsigned short* dinb   = (unsigned short*)(pool + 16008192);
    unsigned short* ctxb   = (unsigned short*)(pool + 16622592);
    // phase D (decoder)
    unsigned short* gatesb = (unsigned short*)(pool + 0);          // 12800x3072 bf16
    unsigned short* h2b    = (unsigned short*)big;                 // 12800x1024 bf16
    unsigned short* h1b    = (unsigned short*)(big + 4000000);     // 12800x1024 bf16
    unsigned short* xcat   = (unsigned short*)(pool + 19899392);
    // weights
    float*          WB     = pool + 23790592;
    unsigned short* cWc  = (unsigned short*)(WB + 0);
    unsigned short* cWif = (unsigned short*)(WB + 1966080);
    unsigned short* cWib = (unsigned short*)(WB + 2228224);
    unsigned short* cWk  = (unsigned short*)(WB + 2490368);
    unsigned short* cWv  = (unsigned short*)(WB + 2621440);
    unsigned short* cWq  = (unsigned short*)(WB + 2752512);
    unsigned short* cWo  = (unsigned short*)(WB + 2777088);
    unsigned short* cW1  = (unsigned short*)(WB + 2908160);
    unsigned short* cW2  = (unsigned short*)(WB + 3842048);
    unsigned short* cWm  = (unsigned short*)(WB + 5414912);   // 128x1024 bf16

    auto ceil256 = [](int n) { return (n + 255) / 256; };

    // zero tagged-word staging (tags must start != 1..256)
    hipMemsetAsync(hstage, 0, 16384 * 4, stream);

    // ---- fused weight conversions (1 launch) ----
    cvt_all<<<ceil256(10960896), 256, 0, stream>>>(
        conv_w, Wih_f, Wih_b, Wk, Wv, Wq, Wo, Wih1, Wih2, melW,
        cWc, cWif, cWib, cWk, cWv, cWq, cWo, cW1, cW2, cWm);

    // ---- encoder: embedding + 3 convs ----
    embed_k<<<ceil256(B_ * S_ * D_), 256, 0, stream>>>(text, emb, P0);
    float* cin = P0;
    float* cout = P1;
    for (int l = 0; l < 3; ++l) {
        im2col_bf<<<ceil256(B_ * S_ * 2560), 256, 0, stream>>>(cin, (unsigned short*)big);
        launch_mfma(stream, (unsigned short*)big, cWc + (size_t)l * 512 * 2560,
                    cout, nullptr, B_ * S_, 512, 2560, 512, 1,
                    conv_b + l * 512, bn_g + l * 512, bn_b + l * 512, bn_m + l * 512, bn_v + l * 512);
        float* tmp = cin; cin = cout; cout = tmp;
    }
    transp_bf<<<ceil256(B_ * S_ * D_), 256, 0, stream>>>(cin, xsT);

    // ---- encoder LSTM ----
    launch_mfma(stream, xsT, cWif, gi_f, b_f, S_ * B_, 1024, 512, 1024);
    launch_mfma(stream, xsT, cWib, gi_b, b_b, S_ * B_, 1024, 512, 1024);
    lstm_persist7<<<4, 1024, 0, stream>>>(gi_f, gi_b, Whh_f, Whh_b, hist, hstage);
    hist2enc<<<ceil256(B_ * S_ * D_), 256, 0, stream>>>(hist, enc_bf);

    // ---- attention projections ----
    launch_mfma(stream, enc_bf, cWk, kbf, bk, B_ * S_, 512, 512, 512, 2);
    launch_mfma(stream, enc_bf, cWv, vT, bv, B_ * S_, 512, 512, 0, 3);
    decin_k2<<<ceil256(B_ * T_ * 96), 256, 0, stream>>>(mel_t, dinb, xcat);
    launch_mfma(stream, dinb, cWq, qbf, bq, B_ * T_, 512, 96, 512, 2);

    // ---- attention ----
    attn_qk<<<dim3(2, 7, 64), 256, 0, stream>>>(qbf, kbf, big);
    attn_sm<<<12800, 256, 0, stream>>>(big, probs);
    attn_pv<<<dim3(1, 7, 64), 256, 0, stream>>>(probs, vT, ctxb);

    // ---- Wo projection -> xcat[:, 0:512) bf16 ----
    launch_mfma(stream, ctxb, cWo, xcat, bo, B_ * T_, 512, 512, 608, 2);

    // ---- decoder (unchunked, bf16 gates, f-gate dropped; N=3072=[i;g;o]) ----
    launch_mfma(stream, xcat, cW1, gatesb, nullptr, B_ * T_, 3072, 608, 3072, 2);
    dec_cellb2<<<ceil256(B_ * T_ * 512), 256, 0, stream>>>(gatesb, b1, h1b, B_ * T_);
    launch_mfma(stream, h1b, cW2, gatesb, nullptr, B_ * T_, 3072, 1024, 3072, 2);
    dec_cellb2<<<ceil256(B_ * T_ * 512), 256, 0, stream>>>(gatesb, b2, h2b, B_ * T_);

    // ---- output heads (mel via MFMA, stop via reduction) ----
    launch_mfma(stream, h2b, cWm, out, melb, B_ * T_, 128, 1024, 80, 4);
    stop_head<<<(B_ * T_) / 4, 256, 0, stream>>>(h2b, stopW, stopb, out + (size_t)B_ * T_ * M_);
}

// Round 10
// 1621.581 us; speedup vs baseline: 1.1753x; 1.1753x over previous
//
#include <hip/hip_runtime.h>
#include <hip/hip_bf16.h>
#include <math.h>

#define B_ 16
#define S_ 256
#define T_ 800
#define V_ 256
#define D_ 512
#define M_ 80
#define H_ 1024
#define NH_ 4
#define HD_ 128
#define EH_ 256

using bf16x8 = __attribute__((ext_vector_type(8))) short;
using f32x4  = __attribute__((ext_vector_type(4))) float;
typedef _Float16 half8 __attribute__((ext_vector_type(8)));

__device__ __forceinline__ float sigf(float x) { return 1.f / (1.f + __expf(-x)); }
__device__ __forceinline__ float tanhfast(float x) {
    float e = __expf(2.f * x);
    return 1.f - 2.f / (e + 1.f);
}

__device__ __forceinline__ unsigned short f2bf(float f) {
    unsigned int u = __float_as_uint(f);
    unsigned int r = (u + 0x7FFFu + ((u >> 16) & 1u)) >> 16;
    return (unsigned short)r;
}
__device__ __forceinline__ float bf2f(unsigned short u) {
    return __uint_as_float(((unsigned int)u) << 16);
}
__device__ __forceinline__ unsigned short h2u(_Float16 x) {
    union { _Float16 f; unsigned short u; } c; c.f = x; return c.u;
}

// LDS-only barrier (no vmcnt drain); sched_barrier fences motion (rule #18).
#define LDS_BAR() do {                                        \
    asm volatile("s_waitcnt lgkmcnt(0)" ::: "memory");        \
    __builtin_amdgcn_s_barrier();                             \
    __builtin_amdgcn_sched_barrier(0);                        \
} while (0)

__device__ __forceinline__ void gl_lds16(const unsigned short* g, unsigned short* l) {
    __builtin_amdgcn_global_load_lds((const __attribute__((address_space(1))) void*)g,
                                     (__attribute__((address_space(3))) void*)l, 16, 0, 0);
}

// ---------------- MFMA bf16 GEMM: C = A(M,K) @ B(N,K)^T --------------------
// epi: 0 fp32(+bias), 1 conv BN+ReLU fp32, 2 bf16(+bias), 3 v^T bf16, 4 fp32 col<80
__global__ __launch_bounds__(256) void gemm_mfma(
    const unsigned short* __restrict__ A, const unsigned short* __restrict__ Bw,
    void* __restrict__ Cv, const float* __restrict__ bias,
    int M, int N, int K, int ldc, int epi,
    const float* __restrict__ cb, const float* __restrict__ gam,
    const float* __restrict__ bet, const float* __restrict__ mu,
    const float* __restrict__ va)
{
    __shared__ unsigned short As[4096];
    __shared__ unsigned short Bs[4096];
    const int tid = threadIdx.x, w = tid >> 6, lane = tid & 63;
    const int bm = blockIdx.y * 128, bn = blockIdx.x * 128;
    const int wr = w >> 1, wc = w & 1;

    f32x4 acc[4][4];
#pragma unroll
    for (int m = 0; m < 4; ++m)
#pragma unroll
        for (int n = 0; n < 4; ++n) acc[m][n] = (f32x4){0.f, 0.f, 0.f, 0.f};

    const int r0 = w * 16 + (lane >> 2);
    const int k8 = (lane & 3) * 8;
    const unsigned short* Ag = A + (size_t)(bm + r0) * K + k8;
    const unsigned short* Bg = Bw + (size_t)(bn + r0) * K + k8;
    unsigned short* Al = As + w * 512;
    unsigned short* Bl = Bs + w * 512;

    for (int k0 = 0; k0 < K; k0 += 32) {
        __syncthreads();
        gl_lds16(Ag + k0, Al);
        gl_lds16(Ag + (size_t)64 * K + k0, Al + 2048);
        gl_lds16(Bg + k0, Bl);
        gl_lds16(Bg + (size_t)64 * K + k0, Bl + 2048);
        __syncthreads();
        bf16x8 a[4], b[4];
#pragma unroll
        for (int m = 0; m < 4; ++m)
            a[m] = *(const bf16x8*)(As + (wr * 64 + m * 16 + (lane & 15)) * 32 + (lane >> 4) * 8);
#pragma unroll
        for (int n = 0; n < 4; ++n)
            b[n] = *(const bf16x8*)(Bs + (wc * 64 + n * 16 + (lane & 15)) * 32 + (lane >> 4) * 8);
#pragma unroll
        for (int m = 0; m < 4; ++m)
#pragma unroll
            for (int n = 0; n < 4; ++n)
                acc[m][n] = __builtin_amdgcn_mfma_f32_16x16x32_bf16(a[m], b[n], acc[m][n], 0, 0, 0);
    }

    const int cr = (lane >> 4) * 4, ccol = lane & 15;
#pragma unroll
    for (int m = 0; m < 4; ++m)
#pragma unroll
        for (int n = 0; n < 4; ++n) {
            const int col = bn + wc * 64 + n * 16 + ccol;
            const float bv = (bias && !(epi == 4 && col >= 80)) ? bias[col] : 0.f;
#pragma unroll
            for (int j = 0; j < 4; ++j) {
                const int row = bm + wr * 64 + m * 16 + cr + j;
                float v = acc[m][n][j] + bv;
                if (epi == 1) {
                    float x = v + cb[col];
                    v = fmaxf(0.f, gam[col] * (x - mu[col]) * rsqrtf(va[col] + 1e-5f) + bet[col]);
                }
                if (epi == 2) {
                    ((unsigned short*)Cv)[(size_t)row * ldc + col] = f2bf(v);
                } else if (epi == 3) {
                    const int bb2 = row >> 8, ss = row & 255, hh = col >> 7, dd = col & 127;
                    ((unsigned short*)Cv)[((size_t)(bb2 * 4 + hh) * 128 + dd) * 256 + ss] = f2bf(v);
                } else if (epi == 4) {
                    if (col < 80) ((float*)Cv)[(size_t)row * ldc + col] = v;
                } else {
                    ((float*)Cv)[(size_t)row * ldc + col] = v;
                }
            }
        }
}

// ---------------- attention QK^T ------------------------------------------
__global__ __launch_bounds__(256) void attn_qk(
    const unsigned short* __restrict__ q, const unsigned short* __restrict__ k,
    float* __restrict__ scores)
{
    __shared__ unsigned short As[4096];
    __shared__ unsigned short Bs[4096];
    const int tid = threadIdx.x, w = tid >> 6, lane = tid & 63;
    const int bm = blockIdx.y * 128, bn = blockIdx.x * 128;
    const int z = blockIdx.z, b = z >> 2, h = z & 3;
    const int wr = w >> 1, wc = w & 1;

    const unsigned short* A  = q + ((size_t)b * T_) * 512 + h * 128;
    const unsigned short* Bw = k + ((size_t)b * S_) * 512 + h * 128;

    f32x4 acc[4][4];
#pragma unroll
    for (int m = 0; m < 4; ++m)
#pragma unroll
        for (int n = 0; n < 4; ++n) acc[m][n] = (f32x4){0.f, 0.f, 0.f, 0.f};

    const int r0 = w * 16 + (lane >> 2);
    const int k8 = (lane & 3) * 8;
    const unsigned short* Ag = A + (size_t)(bm + r0) * 512 + k8;
    const unsigned short* Bg = Bw + (size_t)(bn + r0) * 512 + k8;
    unsigned short* Al = As + w * 512;
    unsigned short* Bl = Bs + w * 512;

    for (int k0 = 0; k0 < 128; k0 += 32) {
        __syncthreads();
        gl_lds16(Ag + k0, Al);
        gl_lds16(Ag + (size_t)64 * 512 + k0, Al + 2048);
        gl_lds16(Bg + k0, Bl);
        gl_lds16(Bg + (size_t)64 * 512 + k0, Bl + 2048);
        __syncthreads();
        bf16x8 a[4], bfr[4];
#pragma unroll
        for (int m = 0; m < 4; ++m)
            a[m] = *(const bf16x8*)(As + (wr * 64 + m * 16 + (lane & 15)) * 32 + (lane >> 4) * 8);
#pragma unroll
        for (int n = 0; n < 4; ++n)
            bfr[n] = *(const bf16x8*)(Bs + (wc * 64 + n * 16 + (lane & 15)) * 32 + (lane >> 4) * 8);
#pragma unroll
        for (int m = 0; m < 4; ++m)
#pragma unroll
            for (int n = 0; n < 4; ++n)
                acc[m][n] = __builtin_amdgcn_mfma_f32_16x16x32_bf16(a[m], bfr[n], acc[m][n], 0, 0, 0);
    }

    const int cr = (lane >> 4) * 4, ccol = lane & 15;
#pragma unroll
    for (int m = 0; m < 4; ++m)
#pragma unroll
        for (int n = 0; n < 4; ++n) {
            const int col = bn + wc * 64 + n * 16 + ccol;
#pragma unroll
            for (int j = 0; j < 4; ++j) {
                const int row = bm + wr * 64 + m * 16 + cr + j;
                if (row < T_)
                    scores[((size_t)z * T_ + row) * 256 + col] = acc[m][n][j] * 0.08838834764831843f;
            }
        }
}

// ---------------- softmax over s (wave per row) ----------------------------
__global__ __launch_bounds__(256) void attn_sm(
    const float* __restrict__ scores, unsigned short* __restrict__ probs)
{
    const int row = blockIdx.x * 4 + (threadIdx.x >> 6);
    const int lane = threadIdx.x & 63;
    const float4 v = *(const float4*)(scores + (size_t)row * 256 + lane * 4);
    float m = fmaxf(fmaxf(v.x, v.y), fmaxf(v.z, v.w));
    for (int off = 32; off; off >>= 1) m = fmaxf(m, __shfl_xor(m, off));
    float ex = __expf(v.x - m), ey = __expf(v.y - m), ez = __expf(v.z - m), ew = __expf(v.w - m);
    float sum = ex + ey + ez + ew;
    for (int off = 32; off; off >>= 1) sum += __shfl_xor(sum, off);
    const float inv = 1.f / sum;
    ushort4 o;
    o.x = f2bf(ex * inv); o.y = f2bf(ey * inv); o.z = f2bf(ez * inv); o.w = f2bf(ew * inv);
    *(ushort4*)(probs + (size_t)row * 256 + lane * 4) = o;
}

// ---------------- attention PV --------------------------------------------
__global__ __launch_bounds__(256) void attn_pv(
    const unsigned short* __restrict__ probs, const unsigned short* __restrict__ vT,
    unsigned short* __restrict__ ctx)
{
    __shared__ unsigned short As[4096];
    __shared__ unsigned short Bs[4096];
    const int tid = threadIdx.x, w = tid >> 6, lane = tid & 63;
    const int bm = blockIdx.y * 128;
    const int z = blockIdx.z, b = z >> 2, h = z & 3;
    const int wr = w >> 1, wc = w & 1;

    const unsigned short* A  = probs + (size_t)z * T_ * 256;
    const unsigned short* Bw = vT + (size_t)z * 128 * 256;

    f32x4 acc[4][4];
#pragma unroll
    for (int m = 0; m < 4; ++m)
#pragma unroll
        for (int n = 0; n < 4; ++n) acc[m][n] = (f32x4){0.f, 0.f, 0.f, 0.f};

    const int r0 = w * 16 + (lane >> 2);
    const int k8 = (lane & 3) * 8;
    const unsigned short* Ag = A + (size_t)(bm + r0) * 256 + k8;
    const unsigned short* Bg = Bw + (size_t)r0 * 256 + k8;
    unsigned short* Al = As + w * 512;
    unsigned short* Bl = Bs + w * 512;

    for (int k0 = 0; k0 < 256; k0 += 32) {
        __syncthreads();
        gl_lds16(Ag + k0, Al);
        gl_lds16(Ag + (size_t)64 * 256 + k0, Al + 2048);
        gl_lds16(Bg + k0, Bl);
        gl_lds16(Bg + (size_t)64 * 256 + k0, Bl + 2048);
        __syncthreads();
        bf16x8 a[4], bfr[4];
#pragma unroll
        for (int m = 0; m < 4; ++m)
            a[m] = *(const bf16x8*)(As + (wr * 64 + m * 16 + (lane & 15)) * 32 + (lane >> 4) * 8);
#pragma unroll
        for (int n = 0; n < 4; ++n)
            bfr[n] = *(const bf16x8*)(Bs + (wc * 64 + n * 16 + (lane & 15)) * 32 + (lane >> 4) * 8);
#pragma unroll
        for (int m = 0; m < 4; ++m)
#pragma unroll
            for (int n = 0; n < 4; ++n)
                acc[m][n] = __builtin_amdgcn_mfma_f32_16x16x32_bf16(a[m], bfr[n], acc[m][n], 0, 0, 0);
    }

    const int cr = (lane >> 4) * 4, ccol = lane & 15;
#pragma unroll
    for (int m = 0; m < 4; ++m)
#pragma unroll
        for (int n = 0; n < 4; ++n) {
            const int col = wc * 64 + n * 16 + ccol;
#pragma unroll
            for (int j = 0; j < 4; ++j) {
                const int row = bm + wr * 64 + m * 16 + cr + j;
                if (row < T_)
                    ctx[((size_t)b * T_ + row) * 512 + h * 128 + col] = f2bf(acc[m][n][j]);
            }
        }
}

// ---------------- elementwise / conversion kernels -------------------------
__global__ void embed_k(const int* __restrict__ txt, const float* __restrict__ emb,
                        float* __restrict__ xs)
{
    int idx = blockIdx.x * 256 + threadIdx.x;
    if (idx >= B_ * S_ * D_) return;
    int bs = idx >> 9, dd = idx & 511;
    xs[idx] = emb[(size_t)txt[bs] * D_ + dd];
}

__global__ void im2col_bf(const float* __restrict__ in, unsigned short* __restrict__ out)
{
    int idx = blockIdx.x * 256 + threadIdx.x;
    if (idx >= B_ * S_ * 2560) return;
    int r = idx / 2560, cc = idx % 2560;
    int din = cc / 5, kk = cc % 5;
    int b = r >> 8, s = r & 255;
    int sp = s + kk - 2;
    float v = (sp >= 0 && sp < S_) ? in[((size_t)b * S_ + sp) * D_ + din] : 0.f;
    out[idx] = f2bf(v);
}

__global__ void transp_bf(const float* __restrict__ in, unsigned short* __restrict__ out)
{
    int idx = blockIdx.x * 256 + threadIdx.x;
    if (idx >= B_ * S_ * D_) return;
    int d = idx & 511;
    int sb = idx >> 9;
    int s = sb >> 4, b = sb & 15;
    out[idx] = f2bf(in[((size_t)b * S_ + s) * D_ + d]);
}

// hist (f16, [dir][b][s][256]) -> enc (bf16, [b][s][512])
__global__ void hist2enc(const _Float16* __restrict__ hist, unsigned short* __restrict__ enc)
{
    int idx = blockIdx.x * 256 + threadIdx.x;
    if (idx >= B_ * S_ * D_) return;
    int d = idx & 511;
    int bs = idx >> 9;
    int b = bs >> 8, s = bs & 255;
    int dir = d >> 8, hid = d & 255;
    enc[idx] = f2bf((float)hist[(((size_t)(dir * 16 + b) * 256 + s) * 256) + hid]);
}

// ---- single fused weight-conversion kernel ----
__global__ void cvt_all(
    const float* __restrict__ conv_w, const float* __restrict__ Wih_f,
    const float* __restrict__ Wih_b, const float* __restrict__ Wk,
    const float* __restrict__ Wv, const float* __restrict__ Wq,
    const float* __restrict__ Wo, const float* __restrict__ Wih1,
    const float* __restrict__ Wih2, const float* __restrict__ melW,
    unsigned short* __restrict__ cWc, unsigned short* __restrict__ cWif,
    unsigned short* __restrict__ cWib, unsigned short* __restrict__ cWk,
    unsigned short* __restrict__ cWv, unsigned short* __restrict__ cWq,
    unsigned short* __restrict__ cWo, unsigned short* __restrict__ cW1,
    unsigned short* __restrict__ cW2, unsigned short* __restrict__ cWm)
{
    int idx = blockIdx.x * 256 + threadIdx.x;
    if (idx < 3932160) { cWc[idx] = f2bf(conv_w[idx]); return; }
    idx -= 3932160;
    if (idx < 524288) { cWif[idx] = f2bf(Wih_f[idx]); return; }
    idx -= 524288;
    if (idx < 524288) { cWib[idx] = f2bf(Wih_b[idx]); return; }
    idx -= 524288;
    if (idx < 262144) { cWk[idx] = f2bf(Wk[idx]); return; }
    idx -= 262144;
    if (idx < 262144) { cWv[idx] = f2bf(Wv[idx]); return; }
    idx -= 262144;
    if (idx < 49152) {
        int r = idx / 96, k = idx - r * 96;
        cWq[idx] = (k < 80) ? f2bf(Wq[(size_t)r * 80 + k]) : 0;
        return;
    }
    idx -= 49152;
    if (idx < 262144) { cWo[idx] = f2bf(Wo[idx]); return; }
    idx -= 262144;
    if (idx < 1867776) {
        int n = idx / 608, k = idx - n * 608;
        int orig = (n < 1024) ? n : n + 1024;
        cW1[idx] = (k < 592) ? f2bf(Wih1[(size_t)orig * 592 + k]) : 0;
        return;
    }
    idx -= 1867776;
    if (idx < 3145728) {
        int n = idx >> 10, k = idx & 1023;
        int orig = (n < 1024) ? n : n + 1024;
        cW2[idx] = f2bf(Wih2[(size_t)orig * 1024 + k]);
        return;
    }
    idx -= 3145728;
    if (idx < 131072) {
        int r = idx >> 10, k = idx & 1023;
        cWm[idx] = (r < 80) ? f2bf(melW[(size_t)r * 1024 + k]) : 0;
        return;
    }
}

__global__ void decin_k2(const float* __restrict__ mel, unsigned short* __restrict__ din,
                         unsigned short* __restrict__ xcat)
{
    int idx = blockIdx.x * 256 + threadIdx.x;
    if (idx >= B_ * T_ * 96) return;
    int r = idx / 96, j = idx - r * 96;
    int b = r / T_, t = r - b * T_;
    float v = (j < M_ && t > 0) ? mel[((size_t)b * T_ + t - 1) * M_ + j] : 0.f;
    unsigned short bv = f2bf(v);
    din[(size_t)r * 96 + j] = bv;
    xcat[(size_t)r * 608 + 512 + j] = bv;
}

// decoder cell: gates bf16 [rows][3072] = [i;g;o], out bf16; 2 cols/thread
__global__ void dec_cellb2(const unsigned short* __restrict__ g, const float* __restrict__ b,
                           unsigned short* __restrict__ h, int rows)
{
    int idx = blockIdx.x * 256 + threadIdx.x;
    if (idx >= rows * 512) return;
    int r = idx >> 9, j2 = (idx & 511) * 2;
    const unsigned short* gr = g + (size_t)r * 3072;
    ushort2 vi = *(const ushort2*)(gr + j2);
    ushort2 vg = *(const ushort2*)(gr + 1024 + j2);
    ushort2 vo = *(const ushort2*)(gr + 2048 + j2);
    float i0 = sigf(bf2f(vi.x) + b[j2]),          i1 = sigf(bf2f(vi.y) + b[j2 + 1]);
    float g0 = tanhfast(bf2f(vg.x) + b[2048 + j2]), g1 = tanhfast(bf2f(vg.y) + b[2048 + j2 + 1]);
    float o0 = sigf(bf2f(vo.x) + b[3072 + j2]),   o1 = sigf(bf2f(vo.y) + b[3072 + j2 + 1]);
    ushort2 o;
    o.x = f2bf(o0 * tanhfast(i0 * g0));
    o.y = f2bf(o1 * tanhfast(i1 * g1));
    *(ushort2*)(h + (size_t)r * 1024 + j2) = o;
}

__global__ __launch_bounds__(256) void stop_head(
    const unsigned short* __restrict__ h2, const float* __restrict__ sw,
    const float* __restrict__ sb, float* __restrict__ out)
{
    int row = blockIdx.x * 4 + (threadIdx.x >> 6);
    int lane = threadIdx.x & 63;
    const unsigned short* hr = h2 + (size_t)row * H_;
    float acc = 0.f;
#pragma unroll
    for (int i = 0; i < H_; i += 64) acc += bf2f(hr[i + lane]) * sw[i + lane];
    for (int off = 32; off; off >>= 1) acc += __shfl_xor(acc, off);
    if (lane == 0) out[row] = acc + sb[0];
}

// ---------------- persistent LSTM: single chain, 2 barriers/step -----------
// r9 A/B pipeline regressed (2x MFMA, 4 barriers, 2 spins). r10 = r7 design
// minus one barrier: update -> own h_lds + publish(u64 tagged) + spin/fill
// partner + gi prefetch -> BAR -> full-K MFMA -> exch -> BAR. One spin, one
// LLC RT, 2 LDS-only barriers, 16 MFMA/step.
__global__ __launch_bounds__(1024, 4) void lstm_persist8(
    const float* __restrict__ gi_f, const float* __restrict__ gi_b,
    const float* __restrict__ Wf, const float* __restrict__ Wb,
    _Float16* __restrict__ hist,               // [2][16][256][256] f16
    unsigned long long* __restrict__ hstage)   // [2 slot][2 dir][2 half][8 ba][128 hid]
{
    const int blk = blockIdx.x;
    const int dir = blk >> 1, half = blk & 1;
    const float* gi = dir ? gi_b : gi_f;
    const float* W  = dir ? Wb : Wf;
    const int tid = threadIdx.x, wid = tid >> 6, lane = tid & 63;
    const int l15 = lane & 15, q = lane >> 4;

    __shared__ _Float16 h_lds[16][264];
    __shared__ float exch[512][17];

    // full-K weight fragments: w0 = gate tile wid, w1 = tile wid+16
    half8 w0[8], w1[8];
    {
        const int gt0 = wid >> 3, hb0 = wid & 7;
        const int gt1 = (wid + 16) >> 3;
        const float* wr0 = W + (size_t)(gt0 * 256 + half * 128 + hb0 * 16 + l15) * 256;
        const float* wr1 = W + (size_t)(gt1 * 256 + half * 128 + hb0 * 16 + l15) * 256;
#pragma unroll
        for (int ks = 0; ks < 8; ++ks) {
            half8 a, b;
#pragma unroll
            for (int j = 0; j < 8; ++j) {
                a[j] = (_Float16)wr0[ks * 32 + q * 8 + j];
                b[j] = (_Float16)wr1[ks * 32 + q * 8 + j];
            }
            w0[ks] = a; w1[ks] = b;
        }
    }
    for (int i = tid; i < 16 * 264; i += 1024) ((_Float16*)h_lds)[i] = (_Float16)0.f;
    for (int i = tid; i < 512 * 17; i += 1024) ((float*)exch)[i] = 0.f;

    const int hid = tid & 127;
    const int ba  = tid >> 7;       // 0..7
    const int bb  = ba + 8;
    const int gh  = half * 128 + hid;
    const int pc  = (half ^ 1) * 128 + hid;
    float c0 = 0.f, c1 = 0.f;

    const int exr0 = (wid >> 3) * 128 + (wid & 7) * 16 + l15;
    const int exr1 = ((wid + 16) >> 3) * 128 + (wid & 7) * 16 + l15;

    const int own_base = ((dir * 2 + half) * 8 + ba) * 128 + hid;
    const int par_base = ((dir * 2 + (half ^ 1)) * 8 + ba) * 128 + hid;

    // gi prefetch for step 0
    float gp0[4], gp1[4];
    {
        const int s0 = dir ? 255 : 0;
        const float* g0 = gi + ((size_t)s0 * 16 + ba) * 1024 + gh;
        const float* g1 = gi + ((size_t)s0 * 16 + bb) * 1024 + gh;
#pragma unroll
        for (int g2 = 0; g2 < 4; ++g2) { gp0[g2] = g0[g2 * 256]; gp1[g2] = g1[g2 * 256]; }
    }
    __syncthreads();

    for (int step = 0; step < 255; ++step) {
        const int s = dir ? (255 - step) : step;
        const unsigned int tag = (unsigned int)(step + 1);
        const int slot = (step & 1) * 4096;

        // ---- update: h(step) from exch (= Whh@h(step-1)) + gi ----
        float h0, h1;
        {
            float xi = exch[hid][ba] + gp0[0];
            float xf = exch[128 + hid][ba] + gp0[1];
            float xg = exch[256 + hid][ba] + gp0[2];
            float xo = exch[384 + hid][ba] + gp0[3];
            float ig = sigf(xi), fg = sigf(xf), gg = tanhfast(xg), og = sigf(xo);
            c0 = fg * c0 + ig * gg; h0 = og * tanhfast(c0);
            xi = exch[hid][bb] + gp1[0];
            xf = exch[128 + hid][bb] + gp1[1];
            xg = exch[256 + hid][bb] + gp1[2];
            xo = exch[384 + hid][bb] + gp1[3];
            ig = sigf(xi); fg = sigf(xf); gg = tanhfast(xg); og = sigf(xo);
            c1 = fg * c1 + ig * gg; h1 = og * tanhfast(c1);
        }
        // own h -> LDS + tagged u64 to LLC + history
        h_lds[ba][gh] = (_Float16)h0;
        h_lds[bb][gh] = (_Float16)h1;
        {
            unsigned int d32 = (unsigned int)h2u((_Float16)h0) |
                               ((unsigned int)h2u((_Float16)h1) << 16);
            unsigned long long wv = ((unsigned long long)tag << 32) | d32;
            __hip_atomic_store(&hstage[slot + own_base], wv,
                               __ATOMIC_RELAXED, __HIP_MEMORY_SCOPE_AGENT);
        }
        hist[(((size_t)(dir * 16 + ba) * 256 + s) * 256) + gh] = (_Float16)h0;
        hist[(((size_t)(dir * 16 + bb) * 256 + s) * 256) + gh] = (_Float16)h1;

        // ---- next-step gi prefetch (issues before/while spinning) ----
        {
            const int s2 = dir ? (254 - step) : (step + 1);
            const float* g0 = gi + ((size_t)s2 * 16 + ba) * 1024 + gh;
            const float* g1 = gi + ((size_t)s2 * 16 + bb) * 1024 + gh;
#pragma unroll
            for (int g2 = 0; g2 < 4; ++g2) { gp0[g2] = g0[g2 * 256]; gp1[g2] = g1[g2 * 256]; }
        }

        // ---- spin on partner tagged word; fill partner half of h_lds ----
        {
            unsigned long long pv;
            do {
                pv = __hip_atomic_load(&hstage[slot + par_base],
                                       __ATOMIC_RELAXED, __HIP_MEMORY_SCOPE_AGENT);
            } while ((unsigned int)(pv >> 32) != tag);
            unsigned int d32 = (unsigned int)pv;
            *(unsigned short*)&h_lds[ba][pc] = (unsigned short)(d32 & 0xFFFF);
            *(unsigned short*)&h_lds[bb][pc] = (unsigned short)(d32 >> 16);
        }
        LDS_BAR();   // all h_lds writes (own + partner) visible

        // ---- full-K MFMA -> exch ----
        {
            f32x4 a0 = (f32x4){0.f, 0.f, 0.f, 0.f};
            f32x4 a1 = (f32x4){0.f, 0.f, 0.f, 0.f};
            const _Float16* hrow = &h_lds[l15][0];
#pragma unroll
            for (int ks = 0; ks < 8; ++ks) {
                half8 a = *(const half8*)(hrow + ks * 32 + q * 8);
                a0 = __builtin_amdgcn_mfma_f32_16x16x32_f16(a, w0[ks], a0, 0, 0, 0);
                a1 = __builtin_amdgcn_mfma_f32_16x16x32_f16(a, w1[ks], a1, 0, 0, 0);
            }
            *(f32x4*)&exch[exr0][q * 4] = a0;
            *(f32x4*)&exch[exr1][q * 4] = a1;
        }
        LDS_BAR();   // exch ready for next update
    }

    // ---- final step 255: update + history only ----
    {
        const int s = dir ? 0 : 255;
        float h0, h1;
        float xi = exch[hid][ba] + gp0[0];
        float xf = exch[128 + hid][ba] + gp0[1];
        float xg = exch[256 + hid][ba] + gp0[2];
        float xo = exch[384 + hid][ba] + gp0[3];
        float ig = sigf(xi), fg = sigf(xf), gg = tanhfast(xg), og = sigf(xo);
        c0 = fg * c0 + ig * gg; h0 = og * tanhfast(c0);
        xi = exch[hid][bb] + gp1[0];
        xf = exch[128 + hid][bb] + gp1[1];
        xg = exch[256 + hid][bb] + gp1[2];
        xo = exch[384 + hid][bb] + gp1[3];
        ig = sigf(xi); fg = sigf(xf); gg = tanhfast(xg); og = sigf(xo);
        c1 = fg * c1 + ig * gg; h1 = og * tanhfast(c1);
        hist[(((size_t)(dir * 16 + ba) * 256 + s) * 256) + gh] = (_Float16)h0;
        hist[(((size_t)(dir * 16 + bb) * 256 + s) * 256) + gh] = (_Float16)h1;
    }
}

// ---------------- host orchestration --------------------------------------
static inline void launch_mfma(hipStream_t st, const unsigned short* A, const unsigned short* B,
                               void* C, const float* bias, int M, int N, int K, int ldc, int epi = 0,
                               const float* cb = nullptr, const float* gam = nullptr,
                               const float* bet = nullptr, const float* mu = nullptr,
                               const float* va = nullptr)
{
    dim3 grid(N / 128, M / 128);
    gemm_mfma<<<grid, 256, 0, st>>>(A, B, C, bias, M, N, K, ldc, epi, cb, gam, bet, mu, va);
}

extern "C" void kernel_launch(void* const* d_in, const int* in_sizes, int n_in,
                              void* d_out, int out_size, void* d_ws, size_t ws_size,
                              hipStream_t stream)
{
    const int*   text   = (const int*)d_in[0];
    const float* mel_t  = (const float*)d_in[1];
    const float* emb    = (const float*)d_in[2];
    const float* conv_w = (const float*)d_in[3];
    const float* conv_b = (const float*)d_in[4];
    const float* bn_g   = (const float*)d_in[5];
    const float* bn_b   = (const float*)d_in[6];
    const float* bn_m   = (const float*)d_in[7];
    const float* bn_v   = (const float*)d_in[8];
    const float* Wih_f  = (const float*)d_in[9];
    const float* Whh_f  = (const float*)d_in[10];
    const float* b_f    = (const float*)d_in[11];
    const float* Wih_b  = (const float*)d_in[12];
    const float* Whh_b  = (const float*)d_in[13];
    const float* b_b    = (const float*)d_in[14];
    const float* Wq     = (const float*)d_in[15];
    const float* bq     = (const float*)d_in[16];
    const float* Wk     = (const float*)d_in[17];
    const float* bk     = (const float*)d_in[18];
    const float* Wv     = (const float*)d_in[19];
    const float* bv     = (const float*)d_in[20];
    const float* Wo     = (const float*)d_in[21];
    const float* bo     = (const float*)d_in[22];
    const float* Wih1   = (const float*)d_in[23];
    const float* b1     = (const float*)d_in[24];
    const float* Wih2   = (const float*)d_in[25];
    const float* b2     = (const float*)d_in[26];
    const float* melW   = (const float*)d_in[27];
    const float* melb   = (const float*)d_in[28];
    const float* stopW  = (const float*)d_in[29];
    const float* stopb  = (const float*)d_in[30];
    float* out = (float*)d_out;
    (void)in_sizes; (void)n_in; (void)out_size; (void)ws_size;

    float* ws = (float*)d_ws;
    float* big  = ws;                       // 13107200 f: im2col | scores | h2b/h1b
    float* pool = ws + 13107200;

    unsigned long long* hstage = (unsigned long long*)(ws + 6000000); // 8192 u64, 64KB

    // phase A/B (encoder)
    float*          gi_f   = pool + 0;
    float*          gi_b   = pool + 4194304;
    unsigned short* enc_bf = (unsigned short*)(pool + 8388608);
    float*          P0     = pool + 9437184;
    float*          P1     = pool + 11534336;
    unsigned short* xsT    = (unsigned short*)(pool + 13631488);
    _Float16*       hist   = (_Float16*)(pool + 14155776);     // 4MB f16
    // phase C (attention)
    unsigned short* kbf    = (unsigned short*)(pool + 0);
    unsigned short* vT     = (unsigned short*)(pool + 1048576);
    unsigned short* qbf    = (unsigned short*)(pool + 2097152);
    unsigned short* probs  = (unsigned short*)(pool + 9437184);
    unsigned short* dinb   = (unsigned short*)(pool + 16008192);
    unsigned short* ctxb   = (unsigned short*)(pool + 16622592);
    // phase D (decoder)
    unsigned short* gatesb = (unsigned short*)(pool + 0);          // 12800x3072 bf16
    unsigned short* h2b    = (unsigned short*)big;                 // 12800x1024 bf16
    unsigned short* h1b    = (unsigned short*)(big + 4000000);     // 12800x1024 bf16
    unsigned short* xcat   = (unsigned short*)(pool + 19899392);
    // weights
    float*          WB     = pool + 23790592;
    unsigned short* cWc  = (unsigned short*)(WB + 0);
    unsigned short* cWif = (unsigned short*)(WB + 1966080);
    unsigned short* cWib = (unsigned short*)(WB + 2228224);
    unsigned short* cWk  = (unsigned short*)(WB + 2490368);
    unsigned short* cWv  = (unsigned short*)(WB + 2621440);
    unsigned short* cWq  = (unsigned short*)(WB + 2752512);
    unsigned short* cWo  = (unsigned short*)(WB + 2777088);
    unsigned short* cW1  = (unsigned short*)(WB + 2908160);
    unsigned short* cW2  = (unsigned short*)(WB + 3842048);
    unsigned short* cWm  = (unsigned short*)(WB + 5414912);   // 128x1024 bf16

    auto ceil256 = [](int n) { return (n + 255) / 256; };

    // zero tagged-word staging (tags must start != 1..256)
    hipMemsetAsync(hstage, 0, 8192 * 8, stream);

    // ---- fused weight conversions (1 launch) ----
    cvt_all<<<ceil256(10960896), 256, 0, stream>>>(
        conv_w, Wih_f, Wih_b, Wk, Wv, Wq, Wo, Wih1, Wih2, melW,
        cWc, cWif, cWib, cWk, cWv, cWq, cWo, cW1, cW2, cWm);

    // ---- encoder: embedding + 3 convs ----
    embed_k<<<ceil256(B_ * S_ * D_), 256, 0, stream>>>(text, emb, P0);
    float* cin = P0;
    float* cout = P1;
    for (int l = 0; l < 3; ++l) {
        im2col_bf<<<ceil256(B_ * S_ * 2560), 256, 0, stream>>>(cin, (unsigned short*)big);
        launch_mfma(stream, (unsigned short*)big, cWc + (size_t)l * 512 * 2560,
                    cout, nullptr, B_ * S_, 512, 2560, 512, 1,
                    conv_b + l * 512, bn_g + l * 512, bn_b + l * 512, bn_m + l * 512, bn_v + l * 512);
        float* tmp = cin; cin = cout; cout = tmp;
    }
    transp_bf<<<ceil256(B_ * S_ * D_), 256, 0, stream>>>(cin, xsT);

    // ---- encoder LSTM ----
    launch_mfma(stream, xsT, cWif, gi_f, b_f, S_ * B_, 1024, 512, 1024);
    launch_mfma(stream, xsT, cWib, gi_b, b_b, S_ * B_, 1024, 512, 1024);
    lstm_persist8<<<4, 1024, 0, stream>>>(gi_f, gi_b, Whh_f, Whh_b, hist, hstage);
    hist2enc<<<ceil256(B_ * S_ * D_), 256, 0, stream>>>(hist, enc_bf);

    // ---- attention projections ----
    launch_mfma(stream, enc_bf, cWk, kbf, bk, B_ * S_, 512, 512, 512, 2);
    launch_mfma(stream, enc_bf, cWv, vT, bv, B_ * S_, 512, 512, 0, 3);
    decin_k2<<<ceil256(B_ * T_ * 96), 256, 0, stream>>>(mel_t, dinb, xcat);
    launch_mfma(stream, dinb, cWq, qbf, bq, B_ * T_, 512, 96, 512, 2);

    // ---- attention ----
    attn_qk<<<dim3(2, 7, 64), 256, 0, stream>>>(qbf, kbf, big);
    attn_sm<<<12800, 256, 0, stream>>>(big, probs);
    attn_pv<<<dim3(1, 7, 64), 256, 0, stream>>>(probs, vT, ctxb);

    // ---- Wo projection -> xcat[:, 0:512) bf16 ----
    launch_mfma(stream, ctxb, cWo, xcat, bo, B_ * T_, 512, 512, 608, 2);

    // ---- decoder (unchunked, bf16 gates, f-gate dropped; N=3072=[i;g;o]) ----
    launch_mfma(stream, xcat, cW1, gatesb, nullptr, B_ * T_, 3072, 608, 3072, 2);
    dec_cellb2<<<ceil256(B_ * T_ * 512), 256, 0, stream>>>(gatesb, b1, h1b, B_ * T_);
    launch_mfma(stream, h1b, cW2, gatesb, nullptr, B_ * T_, 3072, 1024, 3072, 2);
    dec_cellb2<<<ceil256(B_ * T_ * 512), 256, 0, stream>>>(gatesb, b2, h2b, B_ * T_);

    // ---- output heads (mel via MFMA, stop via reduction) ----
    launch_mfma(stream, h2b, cWm, out, melb, B_ * T_, 128, 1024, 80, 4);
    stop_head<<<(B_ * T_) / 4, 256, 0, stream>>>(h2b, stopW, stopb, out + (size_t)B_ * T_ * M_);
}

// Round 11
// 1575.864 us; speedup vs baseline: 1.2094x; 1.0290x over previous
//
#include <hip/hip_runtime.h>
#include <hip/hip_bf16.h>
#include <math.h>

#define B_ 16
#define S_ 256
#define T_ 800
#define V_ 256
#define D_ 512
#define M_ 80
#define H_ 1024
#define NH_ 4
#define HD_ 128
#define EH_ 256

using bf16x8 = __attribute__((ext_vector_type(8))) short;
using f32x4  = __attribute__((ext_vector_type(4))) float;
typedef _Float16 half8 __attribute__((ext_vector_type(8)));

__device__ __forceinline__ float sigf(float x) { return 1.f / (1.f + __expf(-x)); }
__device__ __forceinline__ float tanhfast(float x) {
    float e = __expf(2.f * x);
    return 1.f - 2.f / (e + 1.f);
}

__device__ __forceinline__ unsigned short f2bf(float f) {
    unsigned int u = __float_as_uint(f);
    unsigned int r = (u + 0x7FFFu + ((u >> 16) & 1u)) >> 16;
    return (unsigned short)r;
}
__device__ __forceinline__ float bf2f(unsigned short u) {
    return __uint_as_float(((unsigned int)u) << 16);
}
__device__ __forceinline__ unsigned short h2u(_Float16 x) {
    union { _Float16 f; unsigned short u; } c; c.f = x; return c.u;
}

__device__ __forceinline__ void gl_lds16(const unsigned short* g, unsigned short* l) {
    __builtin_amdgcn_global_load_lds((const __attribute__((address_space(1))) void*)g,
                                     (__attribute__((address_space(3))) void*)l, 16, 0, 0);
}

// ---------------- MFMA bf16 GEMM: C = A(M,K) @ B(N,K)^T --------------------
// epi: 0 fp32(+bias), 1 conv BN+ReLU fp32, 2 bf16(+bias), 3 v^T bf16, 4 fp32 col<80
__global__ __launch_bounds__(256) void gemm_mfma(
    const unsigned short* __restrict__ A, const unsigned short* __restrict__ Bw,
    void* __restrict__ Cv, const float* __restrict__ bias,
    int M, int N, int K, int ldc, int epi,
    const float* __restrict__ cb, const float* __restrict__ gam,
    const float* __restrict__ bet, const float* __restrict__ mu,
    const float* __restrict__ va)
{
    __shared__ unsigned short As[4096];
    __shared__ unsigned short Bs[4096];
    const int tid = threadIdx.x, w = tid >> 6, lane = tid & 63;
    const int bm = blockIdx.y * 128, bn = blockIdx.x * 128;
    const int wr = w >> 1, wc = w & 1;

    f32x4 acc[4][4];
#pragma unroll
    for (int m = 0; m < 4; ++m)
#pragma unroll
        for (int n = 0; n < 4; ++n) acc[m][n] = (f32x4){0.f, 0.f, 0.f, 0.f};

    const int r0 = w * 16 + (lane >> 2);
    const int k8 = (lane & 3) * 8;
    const unsigned short* Ag = A + (size_t)(bm + r0) * K + k8;
    const unsigned short* Bg = Bw + (size_t)(bn + r0) * K + k8;
    unsigned short* Al = As + w * 512;
    unsigned short* Bl = Bs + w * 512;

    for (int k0 = 0; k0 < K; k0 += 32) {
        __syncthreads();
        gl_lds16(Ag + k0, Al);
        gl_lds16(Ag + (size_t)64 * K + k0, Al + 2048);
        gl_lds16(Bg + k0, Bl);
        gl_lds16(Bg + (size_t)64 * K + k0, Bl + 2048);
        __syncthreads();
        bf16x8 a[4], b[4];
#pragma unroll
        for (int m = 0; m < 4; ++m)
            a[m] = *(const bf16x8*)(As + (wr * 64 + m * 16 + (lane & 15)) * 32 + (lane >> 4) * 8);
#pragma unroll
        for (int n = 0; n < 4; ++n)
            b[n] = *(const bf16x8*)(Bs + (wc * 64 + n * 16 + (lane & 15)) * 32 + (lane >> 4) * 8);
#pragma unroll
        for (int m = 0; m < 4; ++m)
#pragma unroll
            for (int n = 0; n < 4; ++n)
                acc[m][n] = __builtin_amdgcn_mfma_f32_16x16x32_bf16(a[m], b[n], acc[m][n], 0, 0, 0);
    }

    const int cr = (lane >> 4) * 4, ccol = lane & 15;
#pragma unroll
    for (int m = 0; m < 4; ++m)
#pragma unroll
        for (int n = 0; n < 4; ++n) {
            const int col = bn + wc * 64 + n * 16 + ccol;
            const float bv = (bias && !(epi == 4 && col >= 80)) ? bias[col] : 0.f;
#pragma unroll
            for (int j = 0; j < 4; ++j) {
                const int row = bm + wr * 64 + m * 16 + cr + j;
                float v = acc[m][n][j] + bv;
                if (epi == 1) {
                    float x = v + cb[col];
                    v = fmaxf(0.f, gam[col] * (x - mu[col]) * rsqrtf(va[col] + 1e-5f) + bet[col]);
                }
                if (epi == 2) {
                    ((unsigned short*)Cv)[(size_t)row * ldc + col] = f2bf(v);
                } else if (epi == 3) {
                    const int bb2 = row >> 8, ss = row & 255, hh = col >> 7, dd = col & 127;
                    ((unsigned short*)Cv)[((size_t)(bb2 * 4 + hh) * 128 + dd) * 256 + ss] = f2bf(v);
                } else if (epi == 4) {
                    if (col < 80) ((float*)Cv)[(size_t)row * ldc + col] = v;
                } else {
                    ((float*)Cv)[(size_t)row * ldc + col] = v;
                }
            }
        }
}

// ---------------- fused attention QK^T + row softmax -----------------------
// Block = 64 q-rows x full 256 k-cols (wave wid owns cols wid*64..+63).
// Row max/sum: 4-lane-group shfl_xor (ccol bits) + LDS cross-wave combine.
__global__ __launch_bounds__(256) void attn_qksm(
    const unsigned short* __restrict__ q, const unsigned short* __restrict__ k,
    unsigned short* __restrict__ probs)
{
    __shared__ unsigned short As[2048];     // 64 rows x 32 k
    __shared__ unsigned short Bs[8192];     // 256 rows x 32 k
    __shared__ float redm[64][4];
    __shared__ float reds[64][4];
    const int tid = threadIdx.x, wid = tid >> 6, lane = tid & 63;
    const int l15 = lane & 15, bq = lane >> 4;
    const int bm = blockIdx.x * 64;
    const int z = blockIdx.y, b = z >> 2, h = z & 3;

    const unsigned short* A  = q + ((size_t)b * T_) * 512 + h * 128;
    const unsigned short* Bw = k + ((size_t)b * S_) * 512 + h * 128;

    f32x4 acc[4][4];
#pragma unroll
    for (int m = 0; m < 4; ++m)
#pragma unroll
        for (int n = 0; n < 4; ++n) acc[m][n] = (f32x4){0.f, 0.f, 0.f, 0.f};

    const int r0 = wid * 16 + (lane >> 2);
    const int k8 = (lane & 3) * 8;

    for (int k0 = 0; k0 < 128; k0 += 32) {
        __syncthreads();
        gl_lds16(A + (size_t)(bm + r0) * 512 + k0 + k8, As + wid * 512);
        gl_lds16(Bw + (size_t)r0 * 512 + k0 + k8,          Bs + wid * 512);
        gl_lds16(Bw + (size_t)(64 + r0) * 512 + k0 + k8,   Bs + 2048 + wid * 512);
        gl_lds16(Bw + (size_t)(128 + r0) * 512 + k0 + k8,  Bs + 4096 + wid * 512);
        gl_lds16(Bw + (size_t)(192 + r0) * 512 + k0 + k8,  Bs + 6144 + wid * 512);
        __syncthreads();
        bf16x8 a[4], bb[4];
#pragma unroll
        for (int m = 0; m < 4; ++m)
            a[m] = *(const bf16x8*)(As + (m * 16 + l15) * 32 + bq * 8);
#pragma unroll
        for (int n = 0; n < 4; ++n)
            bb[n] = *(const bf16x8*)(Bs + (wid * 64 + n * 16 + l15) * 32 + bq * 8);
#pragma unroll
        for (int m = 0; m < 4; ++m)
#pragma unroll
            for (int n = 0; n < 4; ++n)
                acc[m][n] = __builtin_amdgcn_mfma_f32_16x16x32_bf16(a[m], bb[n], acc[m][n], 0, 0, 0);
    }

    const int cr = (lane >> 4) * 4, ccol = lane & 15;
    const float SC = 0.08838834764831843f;

    // ---- per-row max over this wave's 64 cols ----
    float lmax[4][4];
#pragma unroll
    for (int m = 0; m < 4; ++m)
#pragma unroll
        for (int j = 0; j < 4; ++j) {
            float v = fmaxf(fmaxf(acc[m][0][j], acc[m][1][j]),
                            fmaxf(acc[m][2][j], acc[m][3][j]));
#pragma unroll
            for (int off = 1; off < 16; off <<= 1) v = fmaxf(v, __shfl_xor(v, off));
            lmax[m][j] = v;
            if (ccol == 0) redm[m * 16 + cr + j][wid] = v;
        }
    __syncthreads();
    // ---- combine across waves, exp, local sum ----
    float lsum[4][4];
#pragma unroll
    for (int m = 0; m < 4; ++m)
#pragma unroll
        for (int j = 0; j < 4; ++j) {
            const int r = m * 16 + cr + j;
            float mx = fmaxf(fmaxf(redm[r][0], redm[r][1]), fmaxf(redm[r][2], redm[r][3]));
            lmax[m][j] = mx;
            float s = 0.f;
#pragma unroll
            for (int n = 0; n < 4; ++n) {
                float p = __expf((acc[m][n][j] - mx) * SC);
                acc[m][n][j] = p;
                s += p;
            }
#pragma unroll
            for (int off = 1; off < 16; off <<= 1) s += __shfl_xor(s, off);
            lsum[m][j] = s;
            if (ccol == 0) reds[r][wid] = s;
        }
    __syncthreads();
#pragma unroll
    for (int m = 0; m < 4; ++m)
#pragma unroll
        for (int j = 0; j < 4; ++j) {
            const int r = m * 16 + cr + j;
            const int row = bm + r;
            if (row >= T_) continue;
            const float inv = 1.f / (reds[r][0] + reds[r][1] + reds[r][2] + reds[r][3]);
#pragma unroll
            for (int n = 0; n < 4; ++n)
                probs[((size_t)z * T_ + row) * 256 + wid * 64 + n * 16 + ccol] =
                    f2bf(acc[m][n][j] * inv);
        }
}

// ---------------- attention PV --------------------------------------------
__global__ __launch_bounds__(256) void attn_pv(
    const unsigned short* __restrict__ probs, const unsigned short* __restrict__ vT,
    unsigned short* __restrict__ ctx)
{
    __shared__ unsigned short As[4096];
    __shared__ unsigned short Bs[4096];
    const int tid = threadIdx.x, w = tid >> 6, lane = tid & 63;
    const int bm = blockIdx.y * 128;
    const int z = blockIdx.z, b = z >> 2, h = z & 3;
    const int wr = w >> 1, wc = w & 1;

    const unsigned short* A  = probs + (size_t)z * T_ * 256;
    const unsigned short* Bw = vT + (size_t)z * 128 * 256;

    f32x4 acc[4][4];
#pragma unroll
    for (int m = 0; m < 4; ++m)
#pragma unroll
        for (int n = 0; n < 4; ++n) acc[m][n] = (f32x4){0.f, 0.f, 0.f, 0.f};

    const int r0 = w * 16 + (lane >> 2);
    const int k8 = (lane & 3) * 8;
    const unsigned short* Ag = A + (size_t)(bm + r0) * 256 + k8;
    const unsigned short* Bg = Bw + (size_t)r0 * 256 + k8;
    unsigned short* Al = As + w * 512;
    unsigned short* Bl = Bs + w * 512;

    for (int k0 = 0; k0 < 256; k0 += 32) {
        __syncthreads();
        gl_lds16(Ag + k0, Al);
        gl_lds16(Ag + (size_t)64 * 256 + k0, Al + 2048);
        gl_lds16(Bg + k0, Bl);
        gl_lds16(Bg + (size_t)64 * 256 + k0, Bl + 2048);
        __syncthreads();
        bf16x8 a[4], bfr[4];
#pragma unroll
        for (int m = 0; m < 4; ++m)
            a[m] = *(const bf16x8*)(As + (wr * 64 + m * 16 + (lane & 15)) * 32 + (lane >> 4) * 8);
#pragma unroll
        for (int n = 0; n < 4; ++n)
            bfr[n] = *(const bf16x8*)(Bs + (wc * 64 + n * 16 + (lane & 15)) * 32 + (lane >> 4) * 8);
#pragma unroll
        for (int m = 0; m < 4; ++m)
#pragma unroll
            for (int n = 0; n < 4; ++n)
                acc[m][n] = __builtin_amdgcn_mfma_f32_16x16x32_bf16(a[m], bfr[n], acc[m][n], 0, 0, 0);
    }

    const int cr = (lane >> 4) * 4, ccol = lane & 15;
#pragma unroll
    for (int m = 0; m < 4; ++m)
#pragma unroll
        for (int n = 0; n < 4; ++n) {
            const int col = wc * 64 + n * 16 + ccol;
#pragma unroll
            for (int j = 0; j < 4; ++j) {
                const int row = bm + wr * 64 + m * 16 + cr + j;
                if (row < T_)
                    ctx[((size_t)b * T_ + row) * 512 + h * 128 + col] = f2bf(acc[m][n][j]);
            }
        }
}

// ---------------- elementwise / conversion kernels -------------------------
__global__ void embed_k(const int* __restrict__ txt, const float* __restrict__ emb,
                        float* __restrict__ xs)
{
    int idx = blockIdx.x * 256 + threadIdx.x;
    if (idx >= B_ * S_ * D_) return;
    int bs = idx >> 9, dd = idx & 511;
    xs[idx] = emb[(size_t)txt[bs] * D_ + dd];
}

__global__ void im2col_bf(const float* __restrict__ in, unsigned short* __restrict__ out)
{
    int idx = blockIdx.x * 256 + threadIdx.x;
    if (idx >= B_ * S_ * 2560) return;
    int r = idx / 2560, cc = idx % 2560;
    int din = cc / 5, kk = cc % 5;
    int b = r >> 8, s = r & 255;
    int sp = s + kk - 2;
    float v = (sp >= 0 && sp < S_) ? in[((size_t)b * S_ + sp) * D_ + din] : 0.f;
    out[idx] = f2bf(v);
}

__global__ void transp_bf(const float* __restrict__ in, unsigned short* __restrict__ out)
{
    int idx = blockIdx.x * 256 + threadIdx.x;
    if (idx >= B_ * S_ * D_) return;
    int d = idx & 511;
    int sb = idx >> 9;
    int s = sb >> 4, b = sb & 15;
    out[idx] = f2bf(in[((size_t)b * S_ + s) * D_ + d]);
}

// hist (f16, [dir][b][s][256]) -> enc (bf16, [b][s][512])
__global__ void hist2enc(const _Float16* __restrict__ hist, unsigned short* __restrict__ enc)
{
    int idx = blockIdx.x * 256 + threadIdx.x;
    if (idx >= B_ * S_ * D_) return;
    int d = idx & 511;
    int bs = idx >> 9;
    int b = bs >> 8, s = bs & 255;
    int dir = d >> 8, hid = d & 255;
    enc[idx] = f2bf((float)hist[(((size_t)(dir * 16 + b) * 256 + s) * 256) + hid]);
}

// ---- single fused weight-conversion kernel ----
__global__ void cvt_all(
    const float* __restrict__ conv_w, const float* __restrict__ Wih_f,
    const float* __restrict__ Wih_b, const float* __restrict__ Wk,
    const float* __restrict__ Wv, const float* __restrict__ Wq,
    const float* __restrict__ Wo, const float* __restrict__ Wih1,
    const float* __restrict__ Wih2, const float* __restrict__ melW,
    unsigned short* __restrict__ cWc, unsigned short* __restrict__ cWif,
    unsigned short* __restrict__ cWib, unsigned short* __restrict__ cWk,
    unsigned short* __restrict__ cWv, unsigned short* __restrict__ cWq,
    unsigned short* __restrict__ cWo, unsigned short* __restrict__ cW1,
    unsigned short* __restrict__ cW2, unsigned short* __restrict__ cWm)
{
    int idx = blockIdx.x * 256 + threadIdx.x;
    if (idx < 3932160) { cWc[idx] = f2bf(conv_w[idx]); return; }
    idx -= 3932160;
    if (idx < 524288) { cWif[idx] = f2bf(Wih_f[idx]); return; }
    idx -= 524288;
    if (idx < 524288) { cWib[idx] = f2bf(Wih_b[idx]); return; }
    idx -= 524288;
    if (idx < 262144) { cWk[idx] = f2bf(Wk[idx]); return; }
    idx -= 262144;
    if (idx < 262144) { cWv[idx] = f2bf(Wv[idx]); return; }
    idx -= 262144;
    if (idx < 49152) {
        int r = idx / 96, k = idx - r * 96;
        cWq[idx] = (k < 80) ? f2bf(Wq[(size_t)r * 80 + k]) : 0;
        return;
    }
    idx -= 49152;
    if (idx < 262144) { cWo[idx] = f2bf(Wo[idx]); return; }
    idx -= 262144;
    if (idx < 1867776) {
        int n = idx / 608, k = idx - n * 608;
        int orig = (n < 1024) ? n : n + 1024;
        cW1[idx] = (k < 592) ? f2bf(Wih1[(size_t)orig * 592 + k]) : 0;
        return;
    }
    idx -= 1867776;
    if (idx < 3145728) {
        int n = idx >> 10, k = idx & 1023;
        int orig = (n < 1024) ? n : n + 1024;
        cW2[idx] = f2bf(Wih2[(size_t)orig * 1024 + k]);
        return;
    }
    idx -= 3145728;
    if (idx < 131072) {
        int r = idx >> 10, k = idx & 1023;
        cWm[idx] = (r < 80) ? f2bf(melW[(size_t)r * 1024 + k]) : 0;
        return;
    }
}

__global__ void decin_k2(const float* __restrict__ mel, unsigned short* __restrict__ din,
                         unsigned short* __restrict__ xcat)
{
    int idx = blockIdx.x * 256 + threadIdx.x;
    if (idx >= B_ * T_ * 96) return;
    int r = idx / 96, j = idx - r * 96;
    int b = r / T_, t = r - b * T_;
    float v = (j < M_ && t > 0) ? mel[((size_t)b * T_ + t - 1) * M_ + j] : 0.f;
    unsigned short bv = f2bf(v);
    din[(size_t)r * 96 + j] = bv;
    xcat[(size_t)r * 608 + 512 + j] = bv;
}

// decoder cell: gates bf16 [rows][3072] = [i;g;o], out bf16; 2 cols/thread
__global__ void dec_cellb2(const unsigned short* __restrict__ g, const float* __restrict__ b,
                           unsigned short* __restrict__ h, int rows)
{
    int idx = blockIdx.x * 256 + threadIdx.x;
    if (idx >= rows * 512) return;
    int r = idx >> 9, j2 = (idx & 511) * 2;
    const unsigned short* gr = g + (size_t)r * 3072;
    ushort2 vi = *(const ushort2*)(gr + j2);
    ushort2 vg = *(const ushort2*)(gr + 1024 + j2);
    ushort2 vo = *(const ushort2*)(gr + 2048 + j2);
    float i0 = sigf(bf2f(vi.x) + b[j2]),          i1 = sigf(bf2f(vi.y) + b[j2 + 1]);
    float g0 = tanhfast(bf2f(vg.x) + b[2048 + j2]), g1 = tanhfast(bf2f(vg.y) + b[2048 + j2 + 1]);
    float o0 = sigf(bf2f(vo.x) + b[3072 + j2]),   o1 = sigf(bf2f(vo.y) + b[3072 + j2 + 1]);
    ushort2 o;
    o.x = f2bf(o0 * tanhfast(i0 * g0));
    o.y = f2bf(o1 * tanhfast(i1 * g1));
    *(ushort2*)(h + (size_t)r * 1024 + j2) = o;
}

__global__ __launch_bounds__(256) void stop_head(
    const unsigned short* __restrict__ h2, const float* __restrict__ sw,
    const float* __restrict__ sb, float* __restrict__ out)
{
    int row = blockIdx.x * 4 + (threadIdx.x >> 6);
    int lane = threadIdx.x & 63;
    const unsigned short* hr = h2 + (size_t)row * H_;
    float acc = 0.f;
#pragma unroll
    for (int i = 0; i < H_; i += 64) acc += bf2f(hr[i + lane]) * sw[i + lane];
    for (int off = 32; off; off >>= 1) acc += __shfl_xor(acc, off);
    if (lane == 0) out[row] = acc + sb[0];
}

// ---------------- persistent LSTM: r7 structure (best: 696us) --------------
// update -> publish(u64 tagged, FIRST) -> h_lds own + hist + gi prefetch ->
// __syncthreads (gi drain covers RT) -> own-k MFMA -> spin partner -> fill ->
// __syncthreads -> partner-k MFMA -> exch -> __syncthreads.
__global__ __launch_bounds__(1024, 4) void lstm_persist9(
    const float* __restrict__ gi_f, const float* __restrict__ gi_b,
    const float* __restrict__ Wf, const float* __restrict__ Wb,
    _Float16* __restrict__ hist,               // [2][16][256][256] f16
    unsigned long long* __restrict__ hstage)   // [2 slot][2 dir][2 half][8 ba][128 hid]
{
    const int blk = blockIdx.x;
    const int dir = blk >> 1, half = blk & 1;
    const float* gi = dir ? gi_b : gi_f;
    const float* W  = dir ? Wb : Wf;
    const int tid = threadIdx.x, wid = tid >> 6, lane = tid & 63;
    const int l15 = lane & 15, q = lane >> 4;
    const int half4 = half * 4, ph4 = (half ^ 1) * 4;

    __shared__ _Float16 h_lds[16][264];
    __shared__ float exch[512][17];

    // --- preload W fragments, split by own/partner k-range ---
    half8 wOA[4], wPA[4], wOB[4], wPB[4];
    {
        const int gt0 = wid >> 3, hb0 = wid & 7;
        const int gt1 = (wid + 16) >> 3;
        const float* wr0 = W + (size_t)(gt0 * 256 + half * 128 + hb0 * 16 + l15) * 256;
        const float* wr1 = W + (size_t)(gt1 * 256 + half * 128 + hb0 * 16 + l15) * 256;
#pragma unroll
        for (int i = 0; i < 4; ++i) {
            const int kO = (half4 + i) * 32 + q * 8;
            const int kP = (ph4 + i) * 32 + q * 8;
            half8 a, b, c, d;
#pragma unroll
            for (int j = 0; j < 8; ++j) {
                a[j] = (_Float16)wr0[kO + j];
                b[j] = (_Float16)wr0[kP + j];
                c[j] = (_Float16)wr1[kO + j];
                d[j] = (_Float16)wr1[kP + j];
            }
            wOA[i] = a; wPA[i] = b; wOB[i] = c; wPB[i] = d;
        }
    }
    for (int i = tid; i < 16 * 264; i += 1024) ((_Float16*)h_lds)[i] = (_Float16)0.f;
    for (int i = tid; i < 512 * 17; i += 1024) ((float*)exch)[i] = 0.f;

    const int hid = tid & 127;
    const int ba  = tid >> 7;       // 0..7
    const int bb  = ba + 8;
    const int gh  = half * 128 + hid;
    const int pc  = (half ^ 1) * 128 + hid;
    float c0 = 0.f, c1 = 0.f;

    const int exr0 = (wid >> 3) * 128 + (wid & 7) * 16 + l15;
    const int exr1 = ((wid + 16) >> 3) * 128 + (wid & 7) * 16 + l15;

    const int own_base = ((dir * 2 + half) * 8 + ba) * 128 + hid;
    const int par_base = ((dir * 2 + (half ^ 1)) * 8 + ba) * 128 + hid;

    // gi prefetch for step 0
    float gp0[4], gp1[4];
    {
        const int s0 = dir ? 255 : 0;
        const float* g0 = gi + ((size_t)s0 * 16 + ba) * 1024 + gh;
        const float* g1 = gi + ((size_t)s0 * 16 + bb) * 1024 + gh;
#pragma unroll
        for (int g2 = 0; g2 < 4; ++g2) { gp0[g2] = g0[g2 * 256]; gp1[g2] = g1[g2 * 256]; }
    }
    __syncthreads();

    for (int step = 0; step < 256; ++step) {
        const int s = dir ? (255 - step) : step;
        const unsigned int tag = (unsigned int)(step + 1);
        const int slot = (step & 1) * 4096;

        // ---- update: h(step) from exch (= Whh@h(step-1)) + gi ----
        float h0, h1;
        {
            float xi = exch[hid][ba] + gp0[0];
            float xf = exch[128 + hid][ba] + gp0[1];
            float xg = exch[256 + hid][ba] + gp0[2];
            float xo = exch[384 + hid][ba] + gp0[3];
            float ig = sigf(xi), fg = sigf(xf), gg = tanhfast(xg), og = sigf(xo);
            c0 = fg * c0 + ig * gg; h0 = og * tanhfast(c0);
            xi = exch[hid][bb] + gp1[0];
            xf = exch[128 + hid][bb] + gp1[1];
            xg = exch[256 + hid][bb] + gp1[2];
            xo = exch[384 + hid][bb] + gp1[3];
            ig = sigf(xi); fg = sigf(xf); gg = tanhfast(xg); og = sigf(xo);
            c1 = fg * c1 + ig * gg; h1 = og * tanhfast(c1);
        }
        // publish FIRST (max RT cover), then LDS + history + gi prefetch
        {
            unsigned int d32 = (unsigned int)h2u((_Float16)h0) |
                               ((unsigned int)h2u((_Float16)h1) << 16);
            unsigned long long wv = ((unsigned long long)tag << 32) | d32;
            __hip_atomic_store(&hstage[slot + own_base], wv,
                               __ATOMIC_RELAXED, __HIP_MEMORY_SCOPE_AGENT);
        }
        h_lds[ba][gh] = (_Float16)h0;
        h_lds[bb][gh] = (_Float16)h1;
        hist[(((size_t)(dir * 16 + ba) * 256 + s) * 256) + gh] = (_Float16)h0;
        hist[(((size_t)(dir * 16 + bb) * 256 + s) * 256) + gh] = (_Float16)h1;
        if (step < 255) {
            const int s2 = dir ? (254 - step) : (step + 1);
            const float* g0 = gi + ((size_t)s2 * 16 + ba) * 1024 + gh;
            const float* g1 = gi + ((size_t)s2 * 16 + bb) * 1024 + gh;
#pragma unroll
            for (int g2 = 0; g2 < 4; ++g2) { gp0[g2] = g0[g2 * 256]; gp1[g2] = g1[g2 * 256]; }
        }
        __syncthreads();   // own-half h_lds complete (drain covers RT)

        if (step < 255) {
            // ---- MFMA over own k-range (more RT cover) ----
            f32x4 acc0 = (f32x4){0.f, 0.f, 0.f, 0.f};
            f32x4 acc1 = (f32x4){0.f, 0.f, 0.f, 0.f};
            const _Float16* hrow = &h_lds[l15][0];
#pragma unroll
            for (int i = 0; i < 4; ++i) {
                half8 a = *(const half8*)(hrow + (half4 + i) * 32 + q * 8);
                acc0 = __builtin_amdgcn_mfma_f32_16x16x32_f16(a, wOA[i], acc0, 0, 0, 0);
                acc1 = __builtin_amdgcn_mfma_f32_16x16x32_f16(a, wOB[i], acc1, 0, 0, 0);
            }
            // ---- spin on partner tagged word; fill partner half of h_lds ----
            {
                unsigned long long pv;
                do {
                    pv = __hip_atomic_load(&hstage[slot + par_base],
                                           __ATOMIC_RELAXED, __HIP_MEMORY_SCOPE_AGENT);
                } while ((unsigned int)(pv >> 32) != tag);
                unsigned int d32 = (unsigned int)pv;
                *(unsigned short*)&h_lds[ba][pc] = (unsigned short)(d32 & 0xFFFF);
                *(unsigned short*)&h_lds[bb][pc] = (unsigned short)(d32 >> 16);
            }
            __syncthreads();   // partner half complete
            // ---- MFMA over partner k-range ----
#pragma unroll
            for (int i = 0; i < 4; ++i) {
                half8 a = *(const half8*)(hrow + (ph4 + i) * 32 + q * 8);
                acc0 = __builtin_amdgcn_mfma_f32_16x16x32_f16(a, wPA[i], acc0, 0, 0, 0);
                acc1 = __builtin_amdgcn_mfma_f32_16x16x32_f16(a, wPB[i], acc1, 0, 0, 0);
            }
            *(f32x4*)&exch[exr0][q * 4] = acc0;
            *(f32x4*)&exch[exr1][q * 4] = acc1;
            __syncthreads();   // exch ready for next update
        }
    }
}

// ---------------- host orchestration --------------------------------------
static inline void launch_mfma(hipStream_t st, const unsigned short* A, const unsigned short* B,
                               void* C, const float* bias, int M, int N, int K, int ldc, int epi = 0,
                               const float* cb = nullptr, const float* gam = nullptr,
                               const float* bet = nullptr, const float* mu = nullptr,
                               const float* va = nullptr)
{
    dim3 grid(N / 128, M / 128);
    gemm_mfma<<<grid, 256, 0, st>>>(A, B, C, bias, M, N, K, ldc, epi, cb, gam, bet, mu, va);
}

extern "C" void kernel_launch(void* const* d_in, const int* in_sizes, int n_in,
                              void* d_out, int out_size, void* d_ws, size_t ws_size,
                              hipStream_t stream)
{
    const int*   text   = (const int*)d_in[0];
    const float* mel_t  = (const float*)d_in[1];
    const float* emb    = (const float*)d_in[2];
    const float* conv_w = (const float*)d_in[3];
    const float* conv_b = (const float*)d_in[4];
    const float* bn_g   = (const float*)d_in[5];
    const float* bn_b   = (const float*)d_in[6];
    const float* bn_m   = (const float*)d_in[7];
    const float* bn_v   = (const float*)d_in[8];
    const float* Wih_f  = (const float*)d_in[9];
    const float* Whh_f  = (const float*)d_in[10];
    const float* b_f    = (const float*)d_in[11];
    const float* Wih_b  = (const float*)d_in[12];
    const float* Whh_b  = (const float*)d_in[13];
    const float* b_b    = (const float*)d_in[14];
    const float* Wq     = (const float*)d_in[15];
    const float* bq     = (const float*)d_in[16];
    const float* Wk     = (const float*)d_in[17];
    const float* bk     = (const float*)d_in[18];
    const float* Wv     = (const float*)d_in[19];
    const float* bv     = (const float*)d_in[20];
    const float* Wo     = (const float*)d_in[21];
    const float* bo     = (const float*)d_in[22];
    const float* Wih1   = (const float*)d_in[23];
    const float* b1     = (const float*)d_in[24];
    const float* Wih2   = (const float*)d_in[25];
    const float* b2     = (const float*)d_in[26];
    const float* melW   = (const float*)d_in[27];
    const float* melb   = (const float*)d_in[28];
    const float* stopW  = (const float*)d_in[29];
    const float* stopb  = (const float*)d_in[30];
    float* out = (float*)d_out;
    (void)in_sizes; (void)n_in; (void)out_size; (void)ws_size;

    float* ws = (float*)d_ws;
    float* big  = ws;                       // 13107200 f: im2col | h2b/h1b
    float* pool = ws + 13107200;

    unsigned long long* hstage = (unsigned long long*)(ws + 6000000); // 8192 u64, 64KB

    // phase A/B (encoder)
    float*          gi_f   = pool + 0;
    float*          gi_b   = pool + 4194304;
    unsigned short* enc_bf = (unsigned short*)(pool + 8388608);
    float*          P0     = pool + 9437184;
    float*          P1     = pool + 11534336;
    unsigned short* xsT    = (unsigned short*)(pool + 13631488);
    _Float16*       hist   = (_Float16*)(pool + 14155776);     // 4MB f16
    // phase C (attention)
    unsigned short* kbf    = (unsigned short*)(pool + 0);
    unsigned short* vT     = (unsigned short*)(pool + 1048576);
    unsigned short* qbf    = (unsigned short*)(pool + 2097152);
    unsigned short* probs  = (unsigned short*)(pool + 9437184);
    unsigned short* dinb   = (unsigned short*)(pool + 16008192);
    unsigned short* ctxb   = (unsigned short*)(pool + 16622592);
    // phase D (decoder)
    unsigned short* gatesb = (unsigned short*)(pool + 0);          // 12800x3072 bf16
    unsigned short* h2b    = (unsigned short*)big;                 // 12800x1024 bf16
    unsigned short* h1b    = (unsigned short*)(big + 4000000);     // 12800x1024 bf16
    unsigned short* xcat   = (unsigned short*)(pool + 19899392);
    // weights
    float*          WB     = pool + 23790592;
    unsigned short* cWc  = (unsigned short*)(WB + 0);
    unsigned short* cWif = (unsigned short*)(WB + 1966080);
    unsigned short* cWib = (unsigned short*)(WB + 2228224);
    unsigned short* cWk  = (unsigned short*)(WB + 2490368);
    unsigned short* cWv  = (unsigned short*)(WB + 2621440);
    unsigned short* cWq  = (unsigned short*)(WB + 2752512);
    unsigned short* cWo  = (unsigned short*)(WB + 2777088);
    unsigned short* cW1  = (unsigned short*)(WB + 2908160);
    unsigned short* cW2  = (unsigned short*)(WB + 3842048);
    unsigned short* cWm  = (unsigned short*)(WB + 5414912);   // 128x1024 bf16

    auto ceil256 = [](int n) { return (n + 255) / 256; };

    // zero tagged-word staging (tags must start != 1..256)
    hipMemsetAsync(hstage, 0, 8192 * 8, stream);

    // ---- fused weight conversions (1 launch) ----
    cvt_all<<<ceil256(10960896), 256, 0, stream>>>(
        conv_w, Wih_f, Wih_b, Wk, Wv, Wq, Wo, Wih1, Wih2, melW,
        cWc, cWif, cWib, cWk, cWv, cWq, cWo, cW1, cW2, cWm);

    // ---- encoder: embedding + 3 convs ----
    embed_k<<<ceil256(B_ * S_ * D_), 256, 0, stream>>>(text, emb, P0);
    float* cin = P0;
    float* cout = P1;
    for (int l = 0; l < 3; ++l) {
        im2col_bf<<<ceil256(B_ * S_ * 2560), 256, 0, stream>>>(cin, (unsigned short*)big);
        launch_mfma(stream, (unsigned short*)big, cWc + (size_t)l * 512 * 2560,
                    cout, nullptr, B_ * S_, 512, 2560, 512, 1,
                    conv_b + l * 512, bn_g + l * 512, bn_b + l * 512, bn_m + l * 512, bn_v + l * 512);
        float* tmp = cin; cin = cout; cout = tmp;
    }
    transp_bf<<<ceil256(B_ * S_ * D_), 256, 0, stream>>>(cin, xsT);

    // ---- encoder LSTM ----
    launch_mfma(stream, xsT, cWif, gi_f, b_f, S_ * B_, 1024, 512, 1024);
    launch_mfma(stream, xsT, cWib, gi_b, b_b, S_ * B_, 1024, 512, 1024);
    lstm_persist9<<<4, 1024, 0, stream>>>(gi_f, gi_b, Whh_f, Whh_b, hist, hstage);
    hist2enc<<<ceil256(B_ * S_ * D_), 256, 0, stream>>>(hist, enc_bf);

    // ---- attention projections ----
    launch_mfma(stream, enc_bf, cWk, kbf, bk, B_ * S_, 512, 512, 512, 2);
    launch_mfma(stream, enc_bf, cWv, vT, bv, B_ * S_, 512, 512, 0, 3);
    decin_k2<<<ceil256(B_ * T_ * 96), 256, 0, stream>>>(mel_t, dinb, xcat);
    launch_mfma(stream, dinb, cWq, qbf, bq, B_ * T_, 512, 96, 512, 2);

    // ---- attention: fused QK^T+softmax, then PV ----
    attn_qksm<<<dim3(13, 64), 256, 0, stream>>>(qbf, kbf, probs);
    attn_pv<<<dim3(1, 7, 64), 256, 0, stream>>>(probs, vT, ctxb);

    // ---- Wo projection -> xcat[:, 0:512) bf16 ----
    launch_mfma(stream, ctxb, cWo, xcat, bo, B_ * T_, 512, 512, 608, 2);

    // ---- decoder (unchunked, bf16 gates, f-gate dropped; N=3072=[i;g;o]) ----
    launch_mfma(stream, xcat, cW1, gatesb, nullptr, B_ * T_, 3072, 608, 3072, 2);
    dec_cellb2<<<ceil256(B_ * T_ * 512), 256, 0, stream>>>(gatesb, b1, h1b, B_ * T_);
    launch_mfma(stream, h1b, cW2, gatesb, nullptr, B_ * T_, 3072, 1024, 3072, 2);
    dec_cellb2<<<ceil256(B_ * T_ * 512), 256, 0, stream>>>(gatesb, b2, h2b, B_ * T_);

    // ---- output heads (mel via MFMA, stop via reduction) ----
    launch_mfma(stream, h2b, cWm, out, melb, B_ * T_, 128, 1024, 80, 4);
    stop_head<<<(B_ * T_) / 4, 256, 0, stream>>>(h2b, stopW, stopb, out + (size_t)B_ * T_ * M_);
}